// Round 1
// 630.098 us; speedup vs baseline: 1.0536x; 1.0536x over previous
//
#include <hip/hip_runtime.h>

// Problem constants
#define BB   32
#define NT   320      // T rows per batch (= 5*64)
#define LX   704
#define TMPL 128
#define NS   576      // LX - TMPL (= 9*64)
#define CC   768
#define NS2  1152     // 2*NS
#define LN_EPS 1e-5f

typedef __attribute__((ext_vector_type(8))) short short8;   // 8 bf16 (4 VGPRs)
typedef __attribute__((ext_vector_type(4))) float f32x4;
typedef unsigned long long u64;

typedef __attribute__((address_space(3))) void as3_void;
typedef __attribute__((address_space(1))) void as1_void;
#define GLDS16(g, l) __builtin_amdgcn_global_load_lds((const as1_void*)(g), (as3_void*)(l), 16, 0, 0)

__device__ __forceinline__ unsigned short f2bf(float f) {
    union { float f; unsigned u; } v; v.f = f;
    unsigned r = v.u + 0x7FFFu + ((v.u >> 16) & 1u);   // RNE
    return (unsigned short)(r >> 16);
}
__device__ __forceinline__ float bf2f(unsigned short h) {
    union { unsigned u; float f; } v; v.u = ((unsigned)h) << 16;
    return v.f;
}

// ---------------- block reductions (blockDim == 256) ----------------
__device__ __forceinline__ float block_sum256(float v) {
    __shared__ float sm[4];
    #pragma unroll
    for (int o = 32; o > 0; o >>= 1) v += __shfl_down(v, o, 64);
    __syncthreads();
    if ((threadIdx.x & 63) == 0) sm[threadIdx.x >> 6] = v;
    __syncthreads();
    return sm[0] + sm[1] + sm[2] + sm[3];
}
__device__ __forceinline__ float block_max256(float v) {
    __shared__ float sm[4];
    #pragma unroll
    for (int o = 32; o > 0; o >>= 1) v = fmaxf(v, __shfl_down(v, o, 64));
    __syncthreads();
    if ((threadIdx.x & 63) == 0) sm[threadIdx.x >> 6] = v;
    __syncthreads();
    return fmaxf(fmaxf(sm[0], sm[1]), fmaxf(sm[2], sm[3]));
}

// =================== bf16 MFMA GEMM core: BM=64, BN=128, BK=32 ===================
// (kept for the per-batch logits / PV GEMMs where M=320 is not a 128-multiple)
// C(M x N) = alpha * A(M x K, row-major bf16) @ Bt(N x K, row-major bf16)^T
// 256 threads = 4 waves in 2x2; wave tile 32x64 (2x4 MFMA 16x16x32).
// LDS chunk-swizzle: global 16B k-chunk g lives at position p = g ^ ((row>>1)&3)
template<bool F32OUT>
__device__ __forceinline__ void gemm64_core(const short* __restrict__ Ab,
                                            const short* __restrict__ Bb,
                                            void* __restrict__ Cb,
                                            int N, int K, float alpha)
{
    __shared__ short As[64 * 32];    // 4 KB
    __shared__ short Bs[128 * 32];   // 8 KB
    const int m0 = blockIdx.y * 64;
    const int n0 = blockIdx.x * 128;
    const int tid  = threadIdx.x;
    const int lane = tid & 63;
    const int w    = tid >> 6;
    const int wr   = (w >> 1) * 32;   // wave row in tile
    const int wc   = (w & 1) * 64;    // wave col in tile

    const int srow = tid >> 2;
    const int g    = ((tid & 3) ^ ((srow >> 1) & 3)) * 8;
    const short* gA  = Ab + (long)(m0 + srow) * K + g;
    const short* gB0 = Bb + (long)(n0 + srow) * K + g;
    const short* gB1 = gB0 + (long)64 * K;
    short* lA  = As + tid * 8;
    short* lB0 = Bs + tid * 8;
    short* lB1 = Bs + 2048 + tid * 8;

    const int fl = lane & 15;         // m/n within 16-tile
    const int ch = lane >> 4;         // k-chunk index 0..3

    f32x4 acc[2][4] = {};

    for (int k0 = 0; k0 < K; k0 += 32) {
        GLDS16(gA  + k0, lA);
        GLDS16(gB0 + k0, lB0);
        GLDS16(gB1 + k0, lB1);
        __syncthreads();

        short8 af[2], bfv[4];
        #pragma unroll
        for (int mt = 0; mt < 2; ++mt) {
            int row = wr + mt * 16 + fl;
            af[mt] = *(const short8*)(As + row * 32 + ((ch ^ ((row >> 1) & 3)) * 8));
        }
        #pragma unroll
        for (int nt = 0; nt < 4; ++nt) {
            int row = wc + nt * 16 + fl;
            bfv[nt] = *(const short8*)(Bs + row * 32 + ((ch ^ ((row >> 1) & 3)) * 8));
        }
        #pragma unroll
        for (int mt = 0; mt < 2; ++mt)
            #pragma unroll
            for (int nt = 0; nt < 4; ++nt)
                acc[mt][nt] = __builtin_amdgcn_mfma_f32_16x16x32_bf16(
                    af[mt], bfv[nt], acc[mt][nt], 0, 0, 0);
        __syncthreads();
    }

    float* Cf = (float*)Cb;
    unsigned short* Ch = (unsigned short*)Cb;
    const int rq = (lane >> 4) * 4;
    #pragma unroll
    for (int mt = 0; mt < 2; ++mt) {
        #pragma unroll
        for (int r = 0; r < 4; ++r) {
            long ro = (long)(m0 + wr + mt * 16 + rq + r) * N + n0 + wc + fl;
            #pragma unroll
            for (int nt = 0; nt < 4; ++nt) {
                float val = acc[mt][nt][r] * alpha;
                if (F32OUT) Cf[ro + nt * 16] = val;
                else        Ch[ro + nt * 16] = f2bf(val);
            }
        }
    }
}

template<bool F32OUT>
__global__ __launch_bounds__(256) void gemm64(
    const short* __restrict__ A, const short* __restrict__ Bt, void* __restrict__ C,
    int N, int K, long sA, long sB, long sC, float alpha)
{
    const int b = blockIdx.z;
    void* Cb = F32OUT ? (void*)((float*)C + (long)b * sC)
                      : (void*)((unsigned short*)C + (long)b * sC);
    gemm64_core<F32OUT>(A + (long)b * sA, Bt + (long)b * sB, Cb, N, K, alpha);
}

// =================== bf16 MFMA GEMM core: BM=128, BN=128, BK=32 (m97 structure) ===================
// 256 threads = 4 waves in 2x2; wave tile 64x64 (4x4 MFMA 16x16x32).
// 16 MFMA per wave per K-step vs 4 global_load_lds + 2 barriers.
// Same chunk-swizzle as gemm64_core (pre-swizzled global src, swizzled ds_read).
// Ab/Bb must already point at the tile origin (A + m0*K, Bt + n0*K). K % 32 == 0.
__device__ __forceinline__ void gemm128_acc(const short* __restrict__ Ab,
                                            const short* __restrict__ Bb,
                                            int K, f32x4 acc[4][4])
{
    __shared__ short As[128 * 32];   // 8 KB
    __shared__ short Bs[128 * 32];   // 8 KB
    const int tid  = threadIdx.x;
    const int lane = tid & 63;
    const int w    = tid >> 6;
    const int wr   = (w >> 1) * 64;
    const int wc   = (w & 1) * 64;

    // staging: 256 threads x 16B = 4 KB/pass; each 8 KB buffer needs 2 passes.
    const int srow = tid >> 2;                       // 0..63
    const int g    = ((tid & 3) ^ ((srow >> 1) & 3)) * 8;
    const short* gA0 = Ab + (long)srow * K + g;
    const short* gA1 = gA0 + (long)64 * K;
    const short* gB0 = Bb + (long)srow * K + g;
    const short* gB1 = gB0 + (long)64 * K;
    short* lA0 = As + tid * 8;
    short* lA1 = As + 2048 + tid * 8;
    short* lB0 = Bs + tid * 8;
    short* lB1 = Bs + 2048 + tid * 8;

    const int fl = lane & 15;
    const int ch = lane >> 4;

    for (int k0 = 0; k0 < K; k0 += 32) {
        GLDS16(gA0 + k0, lA0);
        GLDS16(gA1 + k0, lA1);
        GLDS16(gB0 + k0, lB0);
        GLDS16(gB1 + k0, lB1);
        __syncthreads();

        short8 af[4], bfv[4];
        #pragma unroll
        for (int mt = 0; mt < 4; ++mt) {
            int row = wr + mt * 16 + fl;
            af[mt] = *(const short8*)(As + row * 32 + ((ch ^ ((row >> 1) & 3)) * 8));
        }
        #pragma unroll
        for (int nt = 0; nt < 4; ++nt) {
            int row = wc + nt * 16 + fl;
            bfv[nt] = *(const short8*)(Bs + row * 32 + ((ch ^ ((row >> 1) & 3)) * 8));
        }
        #pragma unroll
        for (int mt = 0; mt < 4; ++mt)
            #pragma unroll
            for (int nt = 0; nt < 4; ++nt)
                acc[mt][nt] = __builtin_amdgcn_mfma_f32_16x16x32_bf16(
                    af[mt], bfv[nt], acc[mt][nt], 0, 0, 0);
        __syncthreads();
    }
}

// flat GEMM, M % 128 == 0, N % 128 == 0: C[M][N] = alpha * A[M][K] @ Bt[N][K]^T
template<bool F32OUT>
__global__ __launch_bounds__(256) void gemm128(
    const short* __restrict__ A, const short* __restrict__ Bt, void* __restrict__ C,
    int N, int K, float alpha)
{
    const int n0 = blockIdx.x * 128;
    const int m0 = blockIdx.y * 128;
    f32x4 acc[4][4] = {};
    gemm128_acc(A + (long)m0 * K, Bt + (long)n0 * K, K, acc);

    const int tid = threadIdx.x, lane = tid & 63, w = tid >> 6;
    const int wr = (w >> 1) * 64, wc = (w & 1) * 64;
    const int fl = lane & 15, rq = (lane >> 4) * 4;
    float* Cf = (float*)C;
    unsigned short* Ch = (unsigned short*)C;
    #pragma unroll
    for (int mt = 0; mt < 4; ++mt) {
        #pragma unroll
        for (int r = 0; r < 4; ++r) {
            long ro = (long)(m0 + wr + mt * 16 + rq + r) * N + n0 + wc + fl;
            #pragma unroll
            for (int nt = 0; nt < 4; ++nt) {
                float val = acc[mt][nt][r] * alpha;
                if (F32OUT) Cf[ro + nt * 16] = val;
                else        Ch[ro + nt * 16] = f2bf(val);
            }
        }
    }
}

// =================== merged KV projection as ONE flat 128^2 GEMM ===================
// A = xsb||xisb viewed as [2*B*NS = 36864][CC]  (contiguous in workspace)
// Bt = WkT||WvT viewed as [2*CC = 1536][CC]     (contiguous in workspace)
// scatter epilogue: row -> (xs/xi, b, n), col -> (k-buf / v-buf)
__global__ __launch_bounds__(256) void proj_kv(
    const short* __restrict__ X, const short* __restrict__ WkvT,
    unsigned short* __restrict__ kkb, unsigned short* __restrict__ vvb)
{
    const int n0 = blockIdx.x * 128;     // 0..1408
    const int m0 = blockIdx.y * 128;     // 0..36736
    f32x4 acc[4][4] = {};
    gemm128_acc(X + (long)m0 * CC, WkvT + (long)n0 * CC, CC, acc);

    const int tid = threadIdx.x, lane = tid & 63, w = tid >> 6;
    const int wr = (w >> 1) * 64, wc = (w & 1) * 64;
    const int fl = lane & 15, rq = (lane >> 4) * 4;

    unsigned short* base = (n0 < CC) ? kkb : vvb;
    const int j0 = ((n0 < CC) ? n0 : n0 - CC) + wc + fl;

    #pragma unroll
    for (int mt = 0; mt < 4; ++mt) {
        #pragma unroll
        for (int r = 0; r < 4; ++r) {
            int row = m0 + wr + mt * 16 + rq + r;          // 0..36863
            int isxi = (row >= BB * NS) ? 1 : 0;
            int r2 = row - isxi * (BB * NS);
            int b = r2 / NS;
            int n = r2 - b * NS;
            unsigned short* po = base + (long)b * NS2 * CC
                                      + (long)isxi * NS * CC
                                      + (long)n * CC + j0;
            #pragma unroll
            for (int nt = 0; nt < 4; ++nt)
                po[nt * 16] = f2bf(acc[mt][nt][r]);
        }
    }
}

// =================== input converts (fp32 -> bf16), merged ===================
__global__ void conv_in(const float* __restrict__ T, const float* __restrict__ x,
                        const float* __restrict__ xi,
                        unsigned short* __restrict__ Tb, unsigned short* __restrict__ xsb,
                        unsigned short* __restrict__ xisb)
{
    const int which = blockIdx.y;
    long i4 = ((long)blockIdx.x * 256 + threadIdx.x) * 4;
    const float* src; unsigned short* dst; long total; int rows, off, rpb;
    if (which == 0) { src = T;  dst = Tb;   total = (long)BB * NT * CC; rows = NT; off = 0;    rpb = NT; }
    else if (which == 1) { src = x;  dst = xsb;  total = (long)BB * NS * CC; rows = LX; off = TMPL; rpb = NS; }
    else            { src = xi; dst = xisb; total = (long)BB * NS * CC; rows = LX; off = TMPL; rpb = NS; }
    if (i4 >= total) return;
    int c   = (int)(i4 % CC);
    long rw = i4 / CC;
    int t   = (int)(rw % rpb);
    int b   = (int)(rw / rpb);
    const float4 f = *(const float4*)(src + ((long)b * rows + off + t) * CC + c);
    ushort4 o;
    o.x = f2bf(f.x); o.y = f2bf(f.y); o.z = f2bf(f.z); o.w = f2bf(f.w);
    *(ushort4*)(dst + i4) = o;
}

// fp32 W [CC][CC] -> bf16 W^T [CC][CC], 4 weights via blockIdx.z
__global__ void conv_wt4(const float* __restrict__ Wq, const float* __restrict__ Wk,
                         const float* __restrict__ Wv, const float* __restrict__ Wo,
                         unsigned short* __restrict__ WqT, unsigned short* __restrict__ WkT,
                         unsigned short* __restrict__ WvT, unsigned short* __restrict__ WoT)
{
    const float* W; unsigned short* WT;
    switch (blockIdx.z) {
        case 0: W = Wq; WT = WqT; break;
        case 1: W = Wk; WT = WkT; break;
        case 2: W = Wv; WT = WvT; break;
        default: W = Wo; WT = WoT; break;
    }
    __shared__ float tile[32][33];
    const int c0 = blockIdx.x * 32, r0 = blockIdx.y * 32;
    const int tx = threadIdx.x & 31, ty = threadIdx.x >> 5;
    #pragma unroll
    for (int i = 0; i < 4; ++i)
        tile[ty + 8 * i][tx] = W[(long)(r0 + ty + 8 * i) * CC + c0 + tx];
    __syncthreads();
    #pragma unroll
    for (int i = 0; i < 4; ++i)
        WT[(long)(c0 + ty + 8 * i) * CC + r0 + tx] = f2bf(tile[tx][ty + 8 * i]);
}

// bf16 vvb [B][NS2][CC] -> bf16 vvT [B][CC][NS2]
__global__ void trans_vv(const unsigned short* __restrict__ vvb, unsigned short* __restrict__ vvT)
{
    __shared__ unsigned short tile[32][34];
    const int b = blockIdx.z;
    const int n0 = blockIdx.x * 32, c0 = blockIdx.y * 32;
    const int tx = threadIdx.x & 31, ty = threadIdx.x >> 5;
    const long ib = (long)b * NS2 * CC;
    #pragma unroll
    for (int i = 0; i < 4; ++i)
        tile[ty + 8 * i][tx] = vvb[ib + (long)(n0 + ty + 8 * i) * CC + c0 + tx];
    __syncthreads();
    #pragma unroll
    for (int i = 0; i < 4; ++i)
        vvT[ib + (long)(c0 + ty + 8 * i) * NS2 + n0 + tx] = tile[tx][ty + 8 * i];
}

// =================== fused dual softmax + bf16 write + sign-pack ===================
__global__ void softmax_pack(const float* __restrict__ P, unsigned short* __restrict__ Pb,
                             u64* __restrict__ posm, u64* __restrict__ eqm)
{
    const long r = blockIdx.x;          // b*NT + t
    const float* p = P + r * NS2;
    const int tid = threadIdx.x;

    float a0 = p[tid], a1 = p[tid + 256], a2 = (tid < 64) ? p[tid + 512] : -1e30f;
    float m1 = block_max256(fmaxf(fmaxf(a0, a1), a2));
    float e0 = __expf(a0 - m1), e1 = __expf(a1 - m1), e2 = (tid < 64) ? __expf(a2 - m1) : 0.f;
    float s1 = block_sum256(e0 + e1 + e2);
    float i1 = 1.f / s1;
    e0 *= i1; e1 *= i1; e2 *= i1;

    const float* q = p + NS;
    float b0 = q[tid], b1 = q[tid + 256], b2 = (tid < 64) ? q[tid + 512] : -1e30f;
    float m2 = block_max256(fmaxf(fmaxf(b0, b1), b2));
    float f0 = __expf(b0 - m2), f1 = __expf(b1 - m2), f2v = (tid < 64) ? __expf(b2 - m2) : 0.f;
    float s2 = block_sum256(f0 + f1 + f2v);
    float i2 = 1.f / s2;
    f0 *= i2; f1 *= i2; f2v *= i2;

    unsigned short* ob = Pb + r * NS2;
    ob[tid] = f2bf(e0); ob[tid + 256] = f2bf(e1);
    if (tid < 64) ob[tid + 512] = f2bf(e2);
    ob[NS + tid] = f2bf(f0); ob[NS + tid + 256] = f2bf(f1);
    if (tid < 64) ob[NS + tid + 512] = f2bf(f2v);

    u64* pm = posm + r * 9;
    u64* em = eqm  + r * 9;
    const int wv = tid >> 6;
    float d0 = e0 - f0, d1 = e1 - f1, d2 = e2 - f2v;
    u64 P0 = __ballot(d0 > 0.f), E0 = __ballot(d0 == 0.f);
    if ((tid & 63) == 0) { pm[wv] = P0; em[wv] = E0; }
    u64 P1 = __ballot(d1 > 0.f), E1 = __ballot(d1 == 0.f);
    if ((tid & 63) == 0) { pm[4 + wv] = P1; em[4 + wv] = E1; }
    u64 P2 = __ballot(tid < 64 && d2 > 0.f), E2 = __ballot(tid < 64 && d2 == 0.f);
    if (tid == 0) { pm[8] = P2; em[8] = E2; }
}

// =================== fused count + x_s ===================
__global__ void xs_fused(const u64* __restrict__ posm, const u64* __restrict__ eqm,
                         const unsigned short* __restrict__ vvb, float* __restrict__ out)
{
    const int gid = blockIdx.x;          // b*NS + n
    const int b = gid / NS, n = gid - b * NS;
    const int tid = threadIdx.x;
    const int wsel = n >> 6, bit = n & 63;
    float ones = 0.f, eqc = 0.f;
    for (int t = tid; t < NT; t += 256) {
        long o = ((long)(b * NT + t)) * 9 + wsel;
        ones += (float)((posm[o] >> bit) & 1);
        eqc  += (float)((eqm[o]  >> bit) & 1);
    }
    ones = block_sum256(ones);
    eqc  = block_sum256(eqc);
    float rgb = ones * (1.f / NT), e = eqc * (1.f / NT);
    float c1 = rgb + e;
    float c2 = (1.f - rgb - e) + e;
    const unsigned* pv  = (const unsigned*)(vvb + ((long)b * NS2 + n) * CC);
    const unsigned* pvi = (const unsigned*)(vvb + ((long)b * NS2 + n + NS) * CC);
    float* po = out + ((long)b * NS + n) * CC;
    for (int idx = tid; idx < CC / 2; idx += 256) {
        unsigned a = pv[idx], bb = pvi[idx];
        float2 o2;
        o2.x = bf2f((unsigned short)(a & 0xFFFF)) * c1 + bf2f((unsigned short)(bb & 0xFFFF)) * c2;
        o2.y = bf2f((unsigned short)(a >> 16))    * c1 + bf2f((unsigned short)(bb >> 16))    * c2;
        *(float2*)(po + 2 * idx) = o2;
    }
}

// =================== T_new = LayerNorm(T + S2) ===================
__global__ void add_ln(const float* __restrict__ T, const float* __restrict__ S2,
                       const float* __restrict__ gamma, const float* __restrict__ beta,
                       float* __restrict__ out)
{
    const long r = blockIdx.x;            // b*NT + t
    const int tid = threadIdx.x;
    const float* tp = T  + r * CC;
    const float* sp = S2 + r * CC;
    float h[3];
    float sum = 0.f;
    #pragma unroll
    for (int i = 0; i < 3; ++i) {
        h[i] = tp[tid + 256 * i] + sp[tid + 256 * i];
        sum += h[i];
    }
    sum = block_sum256(sum);
    float mu = sum * (1.f / CC);
    float varp = 0.f;
    #pragma unroll
    for (int i = 0; i < 3; ++i) { float d = h[i] - mu; varp += d * d; }
    varp = block_sum256(varp);
    float inv = rsqrtf(varp * (1.f / CC) + LN_EPS);
    #pragma unroll
    for (int i = 0; i < 3; ++i) {
        int c = tid + 256 * i;
        out[r * CC + c] = (h[i] - mu) * inv * gamma[c] + beta[c];
    }
}

// =================== launch ===================
extern "C" void kernel_launch(void* const* d_in, const int* in_sizes, int n_in,
                              void* d_out, int out_size, void* d_ws, size_t ws_size,
                              hipStream_t stream) {
    const float* T     = (const float*)d_in[0];
    const float* x     = (const float*)d_in[1];
    const float* xi    = (const float*)d_in[2];
    const float* Wq    = (const float*)d_in[3];
    const float* Wk    = (const float*)d_in[4];
    const float* Wv    = (const float*)d_in[5];
    const float* Wout  = (const float*)d_in[6];
    const float* gamma = (const float*)d_in[7];
    const float* beta  = (const float*)d_in[8];
    float* out = (float*)d_out;

    // ---- workspace layout (bytes), ~288 MB ----
    const long B_T  = (long)BB * NT * CC * 2;         // 15.7 MB (Tb; later Sb)
    const long B_KK = (long)BB * NS2 * CC * 2;        // 56.6 MB
    const long B_WT = (long)CC * CC * 2;              // 1.18 MB each
    const long B_XS = (long)BB * NS * CC * 2;         // 28.3 MB each; pair overlaid by P fp32 (47.2 MB)
    const long B_PB = (long)BB * NT * NS2 * 2;        // 23.6 MB
    const long B_MK = (long)BB * NT * 9 * 8;          // 0.74 MB each

    char* cur = (char*)d_ws;
    unsigned short* Tb   = (unsigned short*)cur; cur += B_T;
    unsigned short* qb   = (unsigned short*)cur; cur += B_T;
    unsigned short* kkb  = (unsigned short*)cur; cur += B_KK;
    unsigned short* WqT  = (unsigned short*)cur; cur += B_WT;
    unsigned short* WkT  = (unsigned short*)cur; cur += B_WT;   // NOTE: WkT||WvT must stay
    unsigned short* WvT  = (unsigned short*)cur; cur += B_WT;   //       adjacent (proj_kv B operand)
    unsigned short* WoT  = (unsigned short*)cur; cur += B_WT;
    unsigned short* vvb  = (unsigned short*)cur; cur += B_KK;
    unsigned short* vvT  = (unsigned short*)cur; cur += B_KK;
    unsigned short* xsb  = (unsigned short*)cur;                // NOTE: xsb||xisb contiguous
    unsigned short* xisb = xsb + (long)BB * NS * CC;  cur += 2 * B_XS;
    unsigned short* Pb   = (unsigned short*)cur; cur += B_PB;
    u64* posm            = (u64*)cur; cur += B_MK;
    u64* eqm             = (u64*)cur; cur += B_MK;
    if ((size_t)(cur - (char*)d_ws) > ws_size) return;

    float* P  = (float*)xsb;    // xsb/xisb dead after projections; 47.2 <= 56.6 MB
    unsigned short* Sb = Tb;    // Tb dead after q GEMM
    float* S2 = (float*)vvb;    // vvb dead after xs_fused; 31.5 <= 56.6 MB

    const float scale = 1.0f / sqrtf((float)CC);
    dim3 blk(256);

    // 1. converts (2 dispatches)
    conv_in<<<dim3((BB * NS * CC) / 1024, 3), blk, 0, stream>>>(T, x, xi, Tb, xsb, xisb);
    conv_wt4<<<dim3(CC / 32, CC / 32, 4), blk, 0, stream>>>(Wq, Wk, Wv, Wout, WqT, WkT, WvT, WoT);

    // 2. merged KV projections as ONE flat GEMM: M=36864, N=1536, K=768 (3456 blocks)
    proj_kv<<<dim3((2 * CC) / 128, (2 * BB * NS) / 128), blk, 0, stream>>>(
        (const short*)xsb, (const short*)WkT, kkb, vvb);

    // 3. q = T @ Wq  (flat across batch: M = B*NT = 10240)
    gemm128<false><<<dim3(CC / 128, (BB * NT) / 128), blk, 0, stream>>>(
        (const short*)Tb, (const short*)WqT, qb, CC, CC, 1.f);

    // 4. transpose v|vi for PV B operand
    trans_vv<<<dim3(NS2 / 32, CC / 32, BB), blk, 0, stream>>>(vvb, vvT);

    // 5. logits (fp32): P = scale * q @ [k|ki]^T  (per-batch B operand, M=320 -> gemm64)
    gemm64<true><<<dim3(NS2 / 128, NT / 64, BB), blk, 0, stream>>>(
        (const short*)qb, (const short*)kkb, P, NS2, CC,
        (long)NT * CC, (long)NS2 * CC, (long)NT * NS2, scale);

    // 6. dual softmax + bf16 P + sign masks
    softmax_pack<<<BB * NT, blk, 0, stream>>>(P, Pb, posm, eqm);

    // 7. fused count + x_s -> d_out[0 : B*NS*CC]
    xs_fused<<<BB * NS, blk, 0, stream>>>(posm, eqm, vvb, out);

    // 8. S = [aw|awi] @ [v;vi]   (bf16, K=1152, per-batch B operand -> gemm64)
    gemm64<false><<<dim3(CC / 128, NT / 64, BB), blk, 0, stream>>>(
        (const short*)Pb, (const short*)vvT, Sb, CC, NS2,
        (long)NT * NS2, (long)CC * NS2, (long)NT * CC, 1.f);

    // 9. S2 = S @ Wout  (fp32, flat: M = B*NT = 10240)
    gemm128<true><<<dim3(CC / 128, (BB * NT) / 128), blk, 0, stream>>>(
        (const short*)Sb, (const short*)WoT, S2, CC, CC, 1.f);

    // 10. T_new = LN(T + S2) -> d_out tail
    add_ln<<<BB * NT, blk, 0, stream>>>(T, S2, gamma, beta, out + (long)BB * NS * CC);
}

// Round 3
// 616.238 us; speedup vs baseline: 1.0773x; 1.0225x over previous
//
#include <hip/hip_runtime.h>

// Problem constants
#define BB   32
#define NT   320      // T rows per batch (= 5*64)
#define LX   704
#define TMPL 128
#define NS   576      // LX - TMPL (= 9*64)
#define CC   768
#define NS2  1152     // 2*NS
#define LN_EPS 1e-5f

typedef __attribute__((ext_vector_type(8))) short short8;   // 8 bf16 (4 VGPRs)
typedef __attribute__((ext_vector_type(4))) float f32x4;
typedef unsigned long long u64;

typedef __attribute__((address_space(3))) void as3_void;
typedef __attribute__((address_space(1))) void as1_void;
#define GLDS16(g, l) __builtin_amdgcn_global_load_lds((const as1_void*)(g), (as3_void*)(l), 16, 0, 0)

__device__ __forceinline__ unsigned short f2bf(float f) {
    union { float f; unsigned u; } v; v.f = f;
    unsigned r = v.u + 0x7FFFu + ((v.u >> 16) & 1u);   // RNE
    return (unsigned short)(r >> 16);
}
__device__ __forceinline__ float bf2f(unsigned short h) {
    union { unsigned u; float f; } v; v.u = ((unsigned)h) << 16;
    return v.f;
}

// ---------------- block reductions (blockDim == 256) ----------------
__device__ __forceinline__ float block_sum256(float v) {
    __shared__ float sm[4];
    #pragma unroll
    for (int o = 32; o > 0; o >>= 1) v += __shfl_down(v, o, 64);
    __syncthreads();
    if ((threadIdx.x & 63) == 0) sm[threadIdx.x >> 6] = v;
    __syncthreads();
    return sm[0] + sm[1] + sm[2] + sm[3];
}
__device__ __forceinline__ float block_max256(float v) {
    __shared__ float sm[4];
    #pragma unroll
    for (int o = 32; o > 0; o >>= 1) v = fmaxf(v, __shfl_down(v, o, 64));
    __syncthreads();
    if ((threadIdx.x & 63) == 0) sm[threadIdx.x >> 6] = v;
    __syncthreads();
    return fmaxf(fmaxf(sm[0], sm[1]), fmaxf(sm[2], sm[3]));
}

// =================== bf16 MFMA GEMM core: BM=64, BN=128, BK=32 ===================
// (kept for the per-batch logits / PV GEMMs where M=320 is not a 128-multiple)
// C(M x N) = alpha * A(M x K, row-major bf16) @ Bt(N x K, row-major bf16)^T
// 256 threads = 4 waves in 2x2; wave tile 32x64 (2x4 MFMA 16x16x32).
// LDS chunk-swizzle: global 16B k-chunk g lives at position p = g ^ ((row>>1)&3)
template<bool F32OUT>
__device__ __forceinline__ void gemm64_core(const short* __restrict__ Ab,
                                            const short* __restrict__ Bb,
                                            void* __restrict__ Cb,
                                            int N, int K, float alpha)
{
    __shared__ short As[64 * 32];    // 4 KB
    __shared__ short Bs[128 * 32];   // 8 KB
    const int m0 = blockIdx.y * 64;
    const int n0 = blockIdx.x * 128;
    const int tid  = threadIdx.x;
    const int lane = tid & 63;
    const int w    = tid >> 6;
    const int wr   = (w >> 1) * 32;   // wave row in tile
    const int wc   = (w & 1) * 64;    // wave col in tile

    const int srow = tid >> 2;
    const int g    = ((tid & 3) ^ ((srow >> 1) & 3)) * 8;
    const short* gA  = Ab + (long)(m0 + srow) * K + g;
    const short* gB0 = Bb + (long)(n0 + srow) * K + g;
    const short* gB1 = gB0 + (long)64 * K;
    short* lA  = As + tid * 8;
    short* lB0 = Bs + tid * 8;
    short* lB1 = Bs + 2048 + tid * 8;

    const int fl = lane & 15;         // m/n within 16-tile
    const int ch = lane >> 4;         // k-chunk index 0..3

    f32x4 acc[2][4] = {};

    for (int k0 = 0; k0 < K; k0 += 32) {
        GLDS16(gA  + k0, lA);
        GLDS16(gB0 + k0, lB0);
        GLDS16(gB1 + k0, lB1);
        __syncthreads();

        short8 af[2], bfv[4];
        #pragma unroll
        for (int mt = 0; mt < 2; ++mt) {
            int row = wr + mt * 16 + fl;
            af[mt] = *(const short8*)(As + row * 32 + ((ch ^ ((row >> 1) & 3)) * 8));
        }
        #pragma unroll
        for (int nt = 0; nt < 4; ++nt) {
            int row = wc + nt * 16 + fl;
            bfv[nt] = *(const short8*)(Bs + row * 32 + ((ch ^ ((row >> 1) & 3)) * 8));
        }
        #pragma unroll
        for (int mt = 0; mt < 2; ++mt)
            #pragma unroll
            for (int nt = 0; nt < 4; ++nt)
                acc[mt][nt] = __builtin_amdgcn_mfma_f32_16x16x32_bf16(
                    af[mt], bfv[nt], acc[mt][nt], 0, 0, 0);
        __syncthreads();
    }

    float* Cf = (float*)Cb;
    unsigned short* Ch = (unsigned short*)Cb;
    const int rq = (lane >> 4) * 4;
    #pragma unroll
    for (int mt = 0; mt < 2; ++mt) {
        #pragma unroll
        for (int r = 0; r < 4; ++r) {
            long ro = (long)(m0 + wr + mt * 16 + rq + r) * N + n0 + wc + fl;
            #pragma unroll
            for (int nt = 0; nt < 4; ++nt) {
                float val = acc[mt][nt][r] * alpha;
                if (F32OUT) Cf[ro + nt * 16] = val;
                else        Ch[ro + nt * 16] = f2bf(val);
            }
        }
    }
}

template<bool F32OUT>
__global__ __launch_bounds__(256) void gemm64(
    const short* __restrict__ A, const short* __restrict__ Bt, void* __restrict__ C,
    int N, int K, long sA, long sB, long sC, float alpha)
{
    const int b = blockIdx.z;
    void* Cb = F32OUT ? (void*)((float*)C + (long)b * sC)
                      : (void*)((unsigned short*)C + (long)b * sC);
    gemm64_core<F32OUT>(A + (long)b * sA, Bt + (long)b * sB, Cb, N, K, alpha);
}

// =================== bf16 MFMA GEMM core: BM=128, BN=128, BK=32 (m97 structure) ===================
// 256 threads = 4 waves in 2x2; wave tile 64x64 (4x4 MFMA 16x16x32).
// Ab/Bb must already point at the tile origin (A + m0*K, Bt + n0*K). K % 32 == 0.
__device__ __forceinline__ void gemm128_acc(const short* __restrict__ Ab,
                                            const short* __restrict__ Bb,
                                            int K, f32x4 acc[4][4])
{
    __shared__ short As[128 * 32];   // 8 KB
    __shared__ short Bs[128 * 32];   // 8 KB
    const int tid  = threadIdx.x;
    const int lane = tid & 63;
    const int w    = tid >> 6;
    const int wr   = (w >> 1) * 64;
    const int wc   = (w & 1) * 64;

    const int srow = tid >> 2;                       // 0..63
    const int g    = ((tid & 3) ^ ((srow >> 1) & 3)) * 8;
    const short* gA0 = Ab + (long)srow * K + g;
    const short* gA1 = gA0 + (long)64 * K;
    const short* gB0 = Bb + (long)srow * K + g;
    const short* gB1 = gB0 + (long)64 * K;
    short* lA0 = As + tid * 8;
    short* lA1 = As + 2048 + tid * 8;
    short* lB0 = Bs + tid * 8;
    short* lB1 = Bs + 2048 + tid * 8;

    const int fl = lane & 15;
    const int ch = lane >> 4;

    for (int k0 = 0; k0 < K; k0 += 32) {
        GLDS16(gA0 + k0, lA0);
        GLDS16(gA1 + k0, lA1);
        GLDS16(gB0 + k0, lB0);
        GLDS16(gB1 + k0, lB1);
        __syncthreads();

        short8 af[4], bfv[4];
        #pragma unroll
        for (int mt = 0; mt < 4; ++mt) {
            int row = wr + mt * 16 + fl;
            af[mt] = *(const short8*)(As + row * 32 + ((ch ^ ((row >> 1) & 3)) * 8));
        }
        #pragma unroll
        for (int nt = 0; nt < 4; ++nt) {
            int row = wc + nt * 16 + fl;
            bfv[nt] = *(const short8*)(Bs + row * 32 + ((ch ^ ((row >> 1) & 3)) * 8));
        }
        #pragma unroll
        for (int mt = 0; mt < 4; ++mt)
            #pragma unroll
            for (int nt = 0; nt < 4; ++nt)
                acc[mt][nt] = __builtin_amdgcn_mfma_f32_16x16x32_bf16(
                    af[mt], bfv[nt], acc[mt][nt], 0, 0, 0);
        __syncthreads();
    }
}

// XCD-aware bijective swizzle of a linear workgroup id (8 XCDs; requires nwg % 8 == 0).
// Each XCD gets a contiguous chunk -> neighbor tiles share L2. [T1, learn_hip m192/m204]
__device__ __forceinline__ int xcd_swz(int orig, int nwg) {
    int cpx = nwg >> 3;
    return (orig & 7) * cpx + (orig >> 3);
}

// flat GEMM, M % 128 == 0, N % 128 == 0: C[M][N] = alpha * A[M][K] @ Bt[N][K]^T
// 1D grid, n-tile fastest after XCD swizzle.
template<bool F32OUT>
__global__ __launch_bounds__(256) void gemm128(
    const short* __restrict__ A, const short* __restrict__ Bt, void* __restrict__ C,
    int N, int K, int ntiles_n, float alpha)
{
    const int wg = xcd_swz(blockIdx.x, gridDim.x);
    const int n0 = (wg % ntiles_n) * 128;
    const int m0 = (wg / ntiles_n) * 128;
    f32x4 acc[4][4] = {};
    gemm128_acc(A + (long)m0 * K, Bt + (long)n0 * K, K, acc);

    const int tid = threadIdx.x, lane = tid & 63, w = tid >> 6;
    const int wr = (w >> 1) * 64, wc = (w & 1) * 64;
    const int fl = lane & 15, rq = (lane >> 4) * 4;
    float* Cf = (float*)C;
    unsigned short* Ch = (unsigned short*)C;
    #pragma unroll
    for (int mt = 0; mt < 4; ++mt) {
        #pragma unroll
        for (int r = 0; r < 4; ++r) {
            long ro = (long)(m0 + wr + mt * 16 + rq + r) * N + n0 + wc + fl;
            #pragma unroll
            for (int nt = 0; nt < 4; ++nt) {
                float val = acc[mt][nt][r] * alpha;
                if (F32OUT) Cf[ro + nt * 16] = val;
                else        Ch[ro + nt * 16] = f2bf(val);
            }
        }
    }
}

// =================== merged KV projection as ONE flat 128^2 GEMM ===================
// A = xsb||xisb viewed as [2*B*NS = 36864][CC]  (contiguous in workspace)
// Bt = WkT||WvT viewed as [2*CC = 1536][CC]     (contiguous in workspace)
// scatter epilogue: row -> (xs/xi, b, n), col -> (k-buf / v-buf)
// XCD swizzle: 3456 blocks = 8 x 432; each XCD owns 36 contiguous m-tiles x 12 n-tiles
// -> resident A panels (~1.6 MB) + whole B (2.4 MB) fit the 4 MB per-XCD L2.
#define PKV_NT 12      // n-tiles = 1536/128
__global__ __launch_bounds__(256) void proj_kv(
    const short* __restrict__ X, const short* __restrict__ WkvT,
    unsigned short* __restrict__ kkb, unsigned short* __restrict__ vvb)
{
    const int wg = xcd_swz(blockIdx.x, gridDim.x);
    const int n0 = (wg % PKV_NT) * 128;     // 0..1408
    const int m0 = (wg / PKV_NT) * 128;     // 0..36736
    f32x4 acc[4][4] = {};
    gemm128_acc(X + (long)m0 * CC, WkvT + (long)n0 * CC, CC, acc);

    const int tid = threadIdx.x, lane = tid & 63, w = tid >> 6;
    const int wr = (w >> 1) * 64, wc = (w & 1) * 64;
    const int fl = lane & 15, rq = (lane >> 4) * 4;

    unsigned short* base = (n0 < CC) ? kkb : vvb;
    const int j0 = ((n0 < CC) ? n0 : n0 - CC) + wc + fl;

    #pragma unroll
    for (int mt = 0; mt < 4; ++mt) {
        #pragma unroll
        for (int r = 0; r < 4; ++r) {
            int row = m0 + wr + mt * 16 + rq + r;          // 0..36863
            int isxi = (row >= BB * NS) ? 1 : 0;
            int r2 = row - isxi * (BB * NS);
            int b = r2 / NS;
            int n = r2 - b * NS;
            unsigned short* po = base + (long)b * NS2 * CC
                                      + (long)isxi * NS * CC
                                      + (long)n * CC + j0;
            #pragma unroll
            for (int nt = 0; nt < 4; ++nt)
                po[nt * 16] = f2bf(acc[mt][nt][r]);
        }
    }
}

// =================== input converts (fp32 -> bf16), merged ===================
__global__ void conv_in(const float* __restrict__ T, const float* __restrict__ x,
                        const float* __restrict__ xi,
                        unsigned short* __restrict__ Tb, unsigned short* __restrict__ xsb,
                        unsigned short* __restrict__ xisb)
{
    const int which = blockIdx.y;
    long i4 = ((long)blockIdx.x * 256 + threadIdx.x) * 4;
    const float* src; unsigned short* dst; long total; int rows, off, rpb;
    if (which == 0) { src = T;  dst = Tb;   total = (long)BB * NT * CC; rows = NT; off = 0;    rpb = NT; }
    else if (which == 1) { src = x;  dst = xsb;  total = (long)BB * NS * CC; rows = LX; off = TMPL; rpb = NS; }
    else            { src = xi; dst = xisb; total = (long)BB * NS * CC; rows = LX; off = TMPL; rpb = NS; }
    if (i4 >= total) return;
    int c   = (int)(i4 % CC);
    long rw = i4 / CC;
    int t   = (int)(rw % rpb);
    int b   = (int)(rw / rpb);
    const float4 f = *(const float4*)(src + ((long)b * rows + off + t) * CC + c);
    ushort4 o;
    o.x = f2bf(f.x); o.y = f2bf(f.y); o.z = f2bf(f.z); o.w = f2bf(f.w);
    *(ushort4*)(dst + i4) = o;
}

// fp32 W [CC][CC] -> bf16 W^T [CC][CC], 4 weights via blockIdx.z
__global__ void conv_wt4(const float* __restrict__ Wq, const float* __restrict__ Wk,
                         const float* __restrict__ Wv, const float* __restrict__ Wo,
                         unsigned short* __restrict__ WqT, unsigned short* __restrict__ WkT,
                         unsigned short* __restrict__ WvT, unsigned short* __restrict__ WoT)
{
    const float* W; unsigned short* WT;
    switch (blockIdx.z) {
        case 0: W = Wq; WT = WqT; break;
        case 1: W = Wk; WT = WkT; break;
        case 2: W = Wv; WT = WvT; break;
        default: W = Wo; WT = WoT; break;
    }
    __shared__ float tile[32][33];
    const int c0 = blockIdx.x * 32, r0 = blockIdx.y * 32;
    const int tx = threadIdx.x & 31, ty = threadIdx.x >> 5;
    #pragma unroll
    for (int i = 0; i < 4; ++i)
        tile[ty + 8 * i][tx] = W[(long)(r0 + ty + 8 * i) * CC + c0 + tx];
    __syncthreads();
    #pragma unroll
    for (int i = 0; i < 4; ++i)
        WT[(long)(c0 + ty + 8 * i) * CC + r0 + tx] = f2bf(tile[tx][ty + 8 * i]);
}

// bf16 vvb [B][NS2][CC] -> bf16 vvT [B][CC][NS2]
__global__ void trans_vv(const unsigned short* __restrict__ vvb, unsigned short* __restrict__ vvT)
{
    __shared__ unsigned short tile[32][34];
    const int b = blockIdx.z;
    const int n0 = blockIdx.x * 32, c0 = blockIdx.y * 32;
    const int tx = threadIdx.x & 31, ty = threadIdx.x >> 5;
    const long ib = (long)b * NS2 * CC;
    #pragma unroll
    for (int i = 0; i < 4; ++i)
        tile[ty + 8 * i][tx] = vvb[ib + (long)(n0 + ty + 8 * i) * CC + c0 + tx];
    __syncthreads();
    #pragma unroll
    for (int i = 0; i < 4; ++i)
        vvT[ib + (long)(c0 + ty + 8 * i) * NS2 + n0 + tx] = tile[tx][ty + 8 * i];
}

// =================== fused dual softmax + bf16 write + sign-pack ===================
__global__ void softmax_pack(const float* __restrict__ P, unsigned short* __restrict__ Pb,
                             u64* __restrict__ posm, u64* __restrict__ eqm)
{
    const long r = blockIdx.x;          // b*NT + t
    const float* p = P + r * NS2;
    const int tid = threadIdx.x;

    float a0 = p[tid], a1 = p[tid + 256], a2 = (tid < 64) ? p[tid + 512] : -1e30f;
    float m1 = block_max256(fmaxf(fmaxf(a0, a1), a2));
    float e0 = __expf(a0 - m1), e1 = __expf(a1 - m1), e2 = (tid < 64) ? __expf(a2 - m1) : 0.f;
    float s1 = block_sum256(e0 + e1 + e2);
    float i1 = 1.f / s1;
    e0 *= i1; e1 *= i1; e2 *= i1;

    const float* q = p + NS;
    float b0 = q[tid], b1 = q[tid + 256], b2 = (tid < 64) ? q[tid + 512] : -1e30f;
    float m2 = block_max256(fmaxf(fmaxf(b0, b1), b2));
    float f0 = __expf(b0 - m2), f1 = __expf(b1 - m2), f2v = (tid < 64) ? __expf(b2 - m2) : 0.f;
    float s2 = block_sum256(f0 + f1 + f2v);
    float i2 = 1.f / s2;
    f0 *= i2; f1 *= i2; f2v *= i2;

    unsigned short* ob = Pb + r * NS2;
    ob[tid] = f2bf(e0); ob[tid + 256] = f2bf(e1);
    if (tid < 64) ob[tid + 512] = f2bf(e2);
    ob[NS + tid] = f2bf(f0); ob[NS + tid + 256] = f2bf(f1);
    if (tid < 64) ob[NS + tid + 512] = f2bf(f2v);

    u64* pm = posm + r * 9;
    u64* em = eqm  + r * 9;
    const int wv = tid >> 6;
    float d0 = e0 - f0, d1 = e1 - f1, d2 = e2 - f2v;
    u64 P0 = __ballot(d0 > 0.f), E0 = __ballot(d0 == 0.f);
    if ((tid & 63) == 0) { pm[wv] = P0; em[wv] = E0; }
    u64 P1 = __ballot(d1 > 0.f), E1 = __ballot(d1 == 0.f);
    if ((tid & 63) == 0) { pm[4 + wv] = P1; em[4 + wv] = E1; }
    u64 P2 = __ballot(tid < 64 && d2 > 0.f), E2 = __ballot(tid < 64 && d2 == 0.f);
    if (tid == 0) { pm[8] = P2; em[8] = E2; }
}

// =================== fused count + x_s ===================
__global__ void xs_fused(const u64* __restrict__ posm, const u64* __restrict__ eqm,
                         const unsigned short* __restrict__ vvb, float* __restrict__ out)
{
    const int gid = blockIdx.x;          // b*NS + n
    const int b = gid / NS, n = gid - b * NS;
    const int tid = threadIdx.x;
    const int wsel = n >> 6, bit = n & 63;
    float ones = 0.f, eqc = 0.f;
    for (int t = tid; t < NT; t += 256) {
        long o = ((long)(b * NT + t)) * 9 + wsel;
        ones += (float)((posm[o] >> bit) & 1);
        eqc  += (float)((eqm[o]  >> bit) & 1);
    }
    ones = block_sum256(ones);
    eqc  = block_sum256(eqc);
    float rgb = ones * (1.f / NT), e = eqc * (1.f / NT);
    float c1 = rgb + e;
    float c2 = (1.f - rgb - e) + e;
    const unsigned* pv  = (const unsigned*)(vvb + ((long)b * NS2 + n) * CC);
    const unsigned* pvi = (const unsigned*)(vvb + ((long)b * NS2 + n + NS) * CC);
    float* po = out + ((long)b * NS + n) * CC;
    for (int idx = tid; idx < CC / 2; idx += 256) {
        unsigned a = pv[idx], bb = pvi[idx];
        float2 o2;
        o2.x = bf2f((unsigned short)(a & 0xFFFF)) * c1 + bf2f((unsigned short)(bb & 0xFFFF)) * c2;
        o2.y = bf2f((unsigned short)(a >> 16))    * c1 + bf2f((unsigned short)(bb >> 16))    * c2;
        *(float2*)(po + 2 * idx) = o2;
    }
}

// =================== T_new = LayerNorm(T + S2) ===================
__global__ void add_ln(const float* __restrict__ T, const float* __restrict__ S2,
                       const float* __restrict__ gamma, const float* __restrict__ beta,
                       float* __restrict__ out)
{
    const long r = blockIdx.x;            // b*NT + t
    const int tid = threadIdx.x;
    const float* tp = T  + r * CC;
    const float* sp = S2 + r * CC;
    float h[3];
    float sum = 0.f;
    #pragma unroll
    for (int i = 0; i < 3; ++i) {
        h[i] = tp[tid + 256 * i] + sp[tid + 256 * i];
        sum += h[i];
    }
    sum = block_sum256(sum);
    float mu = sum * (1.f / CC);
    float varp = 0.f;
    #pragma unroll
    for (int i = 0; i < 3; ++i) { float d = h[i] - mu; varp += d * d; }
    varp = block_sum256(varp);
    float inv = rsqrtf(varp * (1.f / CC) + LN_EPS);
    #pragma unroll
    for (int i = 0; i < 3; ++i) {
        int c = tid + 256 * i;
        out[r * CC + c] = (h[i] - mu) * inv * gamma[c] + beta[c];
    }
}

// =================== launch ===================
extern "C" void kernel_launch(void* const* d_in, const int* in_sizes, int n_in,
                              void* d_out, int out_size, void* d_ws, size_t ws_size,
                              hipStream_t stream) {
    const float* T     = (const float*)d_in[0];
    const float* x     = (const float*)d_in[1];
    const float* xi    = (const float*)d_in[2];
    const float* Wq    = (const float*)d_in[3];
    const float* Wk    = (const float*)d_in[4];
    const float* Wv    = (const float*)d_in[5];
    const float* Wout  = (const float*)d_in[6];
    const float* gamma = (const float*)d_in[7];
    const float* beta  = (const float*)d_in[8];
    float* out = (float*)d_out;

    // ---- workspace layout (bytes), ~288 MB ----
    const long B_T  = (long)BB * NT * CC * 2;         // 15.7 MB (Tb; later Sb)
    const long B_KK = (long)BB * NS2 * CC * 2;        // 56.6 MB
    const long B_WT = (long)CC * CC * 2;              // 1.18 MB each
    const long B_XS = (long)BB * NS * CC * 2;         // 28.3 MB each; pair overlaid by P fp32 (47.2 MB)
    const long B_PB = (long)BB * NT * NS2 * 2;        // 23.6 MB
    const long B_MK = (long)BB * NT * 9 * 8;          // 0.74 MB each

    char* cur = (char*)d_ws;
    unsigned short* Tb   = (unsigned short*)cur; cur += B_T;
    unsigned short* qb   = (unsigned short*)cur; cur += B_T;
    unsigned short* kkb  = (unsigned short*)cur; cur += B_KK;
    unsigned short* WqT  = (unsigned short*)cur; cur += B_WT;
    unsigned short* WkT  = (unsigned short*)cur; cur += B_WT;   // NOTE: WkT||WvT must stay
    unsigned short* WvT  = (unsigned short*)cur; cur += B_WT;   //       adjacent (proj_kv B operand)
    unsigned short* WoT  = (unsigned short*)cur; cur += B_WT;
    unsigned short* vvb  = (unsigned short*)cur; cur += B_KK;
    unsigned short* vvT  = (unsigned short*)cur; cur += B_KK;
    unsigned short* xsb  = (unsigned short*)cur;                // NOTE: xsb||xisb contiguous
    unsigned short* xisb = xsb + (long)BB * NS * CC;  cur += 2 * B_XS;
    unsigned short* Pb   = (unsigned short*)cur; cur += B_PB;
    u64* posm            = (u64*)cur; cur += B_MK;
    u64* eqm             = (u64*)cur; cur += B_MK;
    if ((size_t)(cur - (char*)d_ws) > ws_size) return;

    float* P  = (float*)xsb;    // xsb/xisb dead after projections; 47.2 <= 56.6 MB
    unsigned short* Sb = Tb;    // Tb dead after q GEMM
    float* S2 = (float*)vvb;    // vvb dead after xs_fused; 31.5 <= 56.6 MB

    const float scale = 1.0f / sqrtf((float)CC);
    dim3 blk(256);

    // 1. converts (2 dispatches)
    conv_in<<<dim3((BB * NS * CC) / 1024, 3), blk, 0, stream>>>(T, x, xi, Tb, xsb, xisb);
    conv_wt4<<<dim3(CC / 32, CC / 32, 4), blk, 0, stream>>>(Wq, Wk, Wv, Wout, WqT, WkT, WvT, WoT);

    // 2. merged KV projections as ONE flat GEMM: M=36864, N=1536, K=768
    //    3456 blocks = 8 XCD chunks x 432, XCD-swizzled inside the kernel.
    proj_kv<<<dim3(((2 * CC) / 128) * ((2 * BB * NS) / 128)), blk, 0, stream>>>(
        (const short*)xsb, (const short*)WkT, kkb, vvb);

    // 3. q = T @ Wq  (flat across batch: M = B*NT = 10240; 480 blocks = 8 x 60)
    gemm128<false><<<dim3((CC / 128) * ((BB * NT) / 128)), blk, 0, stream>>>(
        (const short*)Tb, (const short*)WqT, qb, CC, CC, CC / 128, 1.f);

    // 4. transpose v|vi for PV B operand
    trans_vv<<<dim3(NS2 / 32, CC / 32, BB), blk, 0, stream>>>(vvb, vvT);

    // 5. logits (fp32): P = scale * q @ [k|ki]^T  (per-batch B operand, M=320 -> gemm64)
    gemm64<true><<<dim3(NS2 / 128, NT / 64, BB), blk, 0, stream>>>(
        (const short*)qb, (const short*)kkb, P, NS2, CC,
        (long)NT * CC, (long)NS2 * CC, (long)NT * NS2, scale);

    // 6. dual softmax + bf16 P + sign masks
    softmax_pack<<<BB * NT, blk, 0, stream>>>(P, Pb, posm, eqm);

    // 7. fused count + x_s -> d_out[0 : B*NS*CC]
    xs_fused<<<BB * NS, blk, 0, stream>>>(posm, eqm, vvb, out);

    // 8. S = [aw|awi] @ [v;vi]   (bf16, K=1152, per-batch B operand -> gemm64)
    gemm64<false><<<dim3(CC / 128, NT / 64, BB), blk, 0, stream>>>(
        (const short*)Pb, (const short*)vvT, Sb, CC, NS2,
        (long)NT * NS2, (long)CC * NS2, (long)NT * CC, 1.f);

    // 9. S2 = S @ Wout  (fp32, flat: M = B*NT = 10240)
    gemm128<true><<<dim3((CC / 128) * ((BB * NT) / 128)), blk, 0, stream>>>(
        (const short*)Sb, (const short*)WoT, S2, CC, CC, CC / 128, 1.f);

    // 10. T_new = LN(T + S2) -> d_out tail
    add_ln<<<BB * NT, blk, 0, stream>>>(T, S2, gamma, beta, out + (long)BB * NS * CC);
}

// Round 4
// 611.482 us; speedup vs baseline: 1.0857x; 1.0078x over previous
//
#include <hip/hip_runtime.h>

// Problem constants
#define BB   32
#define NT   320      // T rows per batch (= 5*64)
#define LX   704
#define TMPL 128
#define NS   576      // LX - TMPL (= 9*64)
#define CC   768
#define NS2  1152     // 2*NS
#define LN_EPS 1e-5f

typedef __attribute__((ext_vector_type(8))) short short8;   // 8 bf16 (4 VGPRs)
typedef __attribute__((ext_vector_type(4))) float f32x4;
typedef unsigned long long u64;

typedef __attribute__((address_space(3))) void as3_void;
typedef __attribute__((address_space(1))) void as1_void;
#define GLDS16(g, l) __builtin_amdgcn_global_load_lds((const as1_void*)(g), (as3_void*)(l), 16, 0, 0)

__device__ __forceinline__ unsigned short f2bf(float f) {
    union { float f; unsigned u; } v; v.f = f;
    unsigned r = v.u + 0x7FFFu + ((v.u >> 16) & 1u);   // RNE
    return (unsigned short)(r >> 16);
}
__device__ __forceinline__ float bf2f(unsigned short h) {
    union { unsigned u; float f; } v; v.u = ((unsigned)h) << 16;
    return v.f;
}

// ---------------- block reductions (blockDim == 256) ----------------
__device__ __forceinline__ float block_sum256(float v) {
    __shared__ float sm[4];
    #pragma unroll
    for (int o = 32; o > 0; o >>= 1) v += __shfl_down(v, o, 64);
    __syncthreads();
    if ((threadIdx.x & 63) == 0) sm[threadIdx.x >> 6] = v;
    __syncthreads();
    return sm[0] + sm[1] + sm[2] + sm[3];
}
__device__ __forceinline__ float block_max256(float v) {
    __shared__ float sm[4];
    #pragma unroll
    for (int o = 32; o > 0; o >>= 1) v = fmaxf(v, __shfl_down(v, o, 64));
    __syncthreads();
    if ((threadIdx.x & 63) == 0) sm[threadIdx.x >> 6] = v;
    __syncthreads();
    return fmaxf(fmaxf(sm[0], sm[1]), fmaxf(sm[2], sm[3]));
}

// =================== bf16 MFMA GEMM core: BM=64, BN=128, BK=32 ===================
// (kept for the per-batch logits / PV GEMMs where M=320 is not a 128-multiple)
// C(M x N) = alpha * A(M x K, row-major bf16) @ Bt(N x K, row-major bf16)^T
// 256 threads = 4 waves in 2x2; wave tile 32x64 (2x4 MFMA 16x16x32).
// LDS chunk-swizzle: global 16B k-chunk g lives at position p = g ^ ((row>>1)&3)
template<bool F32OUT>
__device__ __forceinline__ void gemm64_core(const short* __restrict__ Ab,
                                            const short* __restrict__ Bb,
                                            void* __restrict__ Cb,
                                            int N, int K, float alpha)
{
    __shared__ short As[64 * 32];    // 4 KB
    __shared__ short Bs[128 * 32];   // 8 KB
    const int m0 = blockIdx.y * 64;
    const int n0 = blockIdx.x * 128;
    const int tid  = threadIdx.x;
    const int lane = tid & 63;
    const int w    = tid >> 6;
    const int wr   = (w >> 1) * 32;   // wave row in tile
    const int wc   = (w & 1) * 64;    // wave col in tile

    const int srow = tid >> 2;
    const int g    = ((tid & 3) ^ ((srow >> 1) & 3)) * 8;
    const short* gA  = Ab + (long)(m0 + srow) * K + g;
    const short* gB0 = Bb + (long)(n0 + srow) * K + g;
    const short* gB1 = gB0 + (long)64 * K;
    short* lA  = As + tid * 8;
    short* lB0 = Bs + tid * 8;
    short* lB1 = Bs + 2048 + tid * 8;

    const int fl = lane & 15;         // m/n within 16-tile
    const int ch = lane >> 4;         // k-chunk index 0..3

    f32x4 acc[2][4] = {};

    for (int k0 = 0; k0 < K; k0 += 32) {
        GLDS16(gA  + k0, lA);
        GLDS16(gB0 + k0, lB0);
        GLDS16(gB1 + k0, lB1);
        __syncthreads();

        short8 af[2], bfv[4];
        #pragma unroll
        for (int mt = 0; mt < 2; ++mt) {
            int row = wr + mt * 16 + fl;
            af[mt] = *(const short8*)(As + row * 32 + ((ch ^ ((row >> 1) & 3)) * 8));
        }
        #pragma unroll
        for (int nt = 0; nt < 4; ++nt) {
            int row = wc + nt * 16 + fl;
            bfv[nt] = *(const short8*)(Bs + row * 32 + ((ch ^ ((row >> 1) & 3)) * 8));
        }
        #pragma unroll
        for (int mt = 0; mt < 2; ++mt)
            #pragma unroll
            for (int nt = 0; nt < 4; ++nt)
                acc[mt][nt] = __builtin_amdgcn_mfma_f32_16x16x32_bf16(
                    af[mt], bfv[nt], acc[mt][nt], 0, 0, 0);
        __syncthreads();
    }

    float* Cf = (float*)Cb;
    unsigned short* Ch = (unsigned short*)Cb;
    const int rq = (lane >> 4) * 4;
    #pragma unroll
    for (int mt = 0; mt < 2; ++mt) {
        #pragma unroll
        for (int r = 0; r < 4; ++r) {
            long ro = (long)(m0 + wr + mt * 16 + rq + r) * N + n0 + wc + fl;
            #pragma unroll
            for (int nt = 0; nt < 4; ++nt) {
                float val = acc[mt][nt][r] * alpha;
                if (F32OUT) Cf[ro + nt * 16] = val;
                else        Ch[ro + nt * 16] = f2bf(val);
            }
        }
    }
}

template<bool F32OUT>
__global__ __launch_bounds__(256) void gemm64(
    const short* __restrict__ A, const short* __restrict__ Bt, void* __restrict__ C,
    int N, int K, long sA, long sB, long sC, float alpha)
{
    const int b = blockIdx.z;
    void* Cb = F32OUT ? (void*)((float*)C + (long)b * sC)
                      : (void*)((unsigned short*)C + (long)b * sC);
    gemm64_core<F32OUT>(A + (long)b * sA, Bt + (long)b * sB, Cb, N, K, alpha);
}

// =================== bf16 MFMA GEMM core: BM=128, BN=128, BK=32 (m97 structure) ===================
// 256 threads = 4 waves in 2x2; wave tile 64x64 (4x4 MFMA 16x16x32).
// Ab/Bb must already point at the tile origin (A + m0*K, Bt + n0*K). K % 32 == 0.
__device__ __forceinline__ void gemm128_acc(const short* __restrict__ Ab,
                                            const short* __restrict__ Bb,
                                            int K, f32x4 acc[4][4])
{
    __shared__ short As[128 * 32];   // 8 KB
    __shared__ short Bs[128 * 32];   // 8 KB
    const int tid  = threadIdx.x;
    const int lane = tid & 63;
    const int w    = tid >> 6;
    const int wr   = (w >> 1) * 64;
    const int wc   = (w & 1) * 64;

    const int srow = tid >> 2;                       // 0..63
    const int g    = ((tid & 3) ^ ((srow >> 1) & 3)) * 8;
    const short* gA0 = Ab + (long)srow * K + g;
    const short* gA1 = gA0 + (long)64 * K;
    const short* gB0 = Bb + (long)srow * K + g;
    const short* gB1 = gB0 + (long)64 * K;
    short* lA0 = As + tid * 8;
    short* lA1 = As + 2048 + tid * 8;
    short* lB0 = Bs + tid * 8;
    short* lB1 = Bs + 2048 + tid * 8;

    const int fl = lane & 15;
    const int ch = lane >> 4;

    for (int k0 = 0; k0 < K; k0 += 32) {
        GLDS16(gA0 + k0, lA0);
        GLDS16(gA1 + k0, lA1);
        GLDS16(gB0 + k0, lB0);
        GLDS16(gB1 + k0, lB1);
        __syncthreads();

        short8 af[4], bfv[4];
        #pragma unroll
        for (int mt = 0; mt < 4; ++mt) {
            int row = wr + mt * 16 + fl;
            af[mt] = *(const short8*)(As + row * 32 + ((ch ^ ((row >> 1) & 3)) * 8));
        }
        #pragma unroll
        for (int nt = 0; nt < 4; ++nt) {
            int row = wc + nt * 16 + fl;
            bfv[nt] = *(const short8*)(Bs + row * 32 + ((ch ^ ((row >> 1) & 3)) * 8));
        }
        #pragma unroll
        for (int mt = 0; mt < 4; ++mt)
            #pragma unroll
            for (int nt = 0; nt < 4; ++nt)
                acc[mt][nt] = __builtin_amdgcn_mfma_f32_16x16x32_bf16(
                    af[mt], bfv[nt], acc[mt][nt], 0, 0, 0);
        __syncthreads();
    }
}

// XCD-aware bijective swizzle of a linear workgroup id (8 XCDs; requires nwg % 8 == 0).
// Each XCD gets a contiguous chunk -> neighbor tiles share L2. [T1, learn_hip m192/m204]
__device__ __forceinline__ int xcd_swz(int orig, int nwg) {
    int cpx = nwg >> 3;
    return (orig & 7) * cpx + (orig >> 3);
}

// flat GEMM, M % 128 == 0, N % 128 == 0: C[M][N] = alpha * A[M][K] @ Bt[N][K]^T
// 1D grid, n-tile fastest after XCD swizzle.
// launch_bounds(256,4): force <=128 total regs/wave -> 4 waves/SIMD (vs 3 at 136).
template<bool F32OUT>
__global__ __launch_bounds__(256, 4) void gemm128(
    const short* __restrict__ A, const short* __restrict__ Bt, void* __restrict__ C,
    int N, int K, int ntiles_n, float alpha)
{
    const int wg = xcd_swz(blockIdx.x, gridDim.x);
    const int n0 = (wg % ntiles_n) * 128;
    const int m0 = (wg / ntiles_n) * 128;
    f32x4 acc[4][4] = {};
    gemm128_acc(A + (long)m0 * K, Bt + (long)n0 * K, K, acc);

    const int tid = threadIdx.x, lane = tid & 63, w = tid >> 6;
    const int wr = (w >> 1) * 64, wc = (w & 1) * 64;
    const int fl = lane & 15, rq = (lane >> 4) * 4;
    float* Cf = (float*)C;
    unsigned short* Ch = (unsigned short*)C;
    #pragma unroll
    for (int mt = 0; mt < 4; ++mt) {
        #pragma unroll
        for (int r = 0; r < 4; ++r) {
            long ro = (long)(m0 + wr + mt * 16 + rq + r) * N + n0 + wc + fl;
            #pragma unroll
            for (int nt = 0; nt < 4; ++nt) {
                float val = acc[mt][nt][r] * alpha;
                if (F32OUT) Cf[ro + nt * 16] = val;
                else        Ch[ro + nt * 16] = f2bf(val);
            }
        }
    }
}

// =================== merged KV projection as ONE flat 128^2 GEMM ===================
// A = xsb||xisb viewed as [2*B*NS = 36864][CC]  (contiguous in workspace)
// Bt = WkT||WvT viewed as [2*CC = 1536][CC]     (contiguous in workspace)
// scatter epilogue: row -> (xs/xi, b, n), col -> (k-buf / v-buf)
// v-half additionally dual-writes the TRANSPOSED layout vvT[b][c][n_global]
// (each lane's 4 acc regs = 4 consecutive n at one col -> packed ushort4 store),
// which eliminates the separate trans_vv kernel.
// XCD swizzle: 3456 blocks = 8 x 432.
#define PKV_NT 12      // n-tiles = 1536/128
__global__ __launch_bounds__(256, 4) void proj_kv(
    const short* __restrict__ X, const short* __restrict__ WkvT,
    unsigned short* __restrict__ kkb, unsigned short* __restrict__ vvb,
    unsigned short* __restrict__ vvT)
{
    const int wg = xcd_swz(blockIdx.x, gridDim.x);
    const int n0 = (wg % PKV_NT) * 128;     // 0..1408
    const int m0 = (wg / PKV_NT) * 128;     // 0..36736
    f32x4 acc[4][4] = {};
    gemm128_acc(X + (long)m0 * CC, WkvT + (long)n0 * CC, CC, acc);

    const int tid = threadIdx.x, lane = tid & 63, w = tid >> 6;
    const int wr = (w >> 1) * 64, wc = (w & 1) * 64;
    const int fl = lane & 15, rq = (lane >> 4) * 4;

    const bool isv = (n0 >= CC);
    unsigned short* base = isv ? vvb : kkb;
    const int j0 = (isv ? n0 - CC : n0) + wc + fl;

    #pragma unroll
    for (int mt = 0; mt < 4; ++mt) {
        // rows rq..rq+3 stay within one (b, isxi) group: 16 | NS and 16 | BB*NS.
        const int row0 = m0 + wr + mt * 16 + rq;
        const int isxi = (row0 >= BB * NS) ? 1 : 0;
        const int r2   = row0 - isxi * (BB * NS);
        const int b    = r2 / NS;
        const int n    = r2 - b * NS;
        unsigned short* po = base + (long)b * NS2 * CC
                                  + (long)isxi * NS * CC
                                  + (long)n * CC + j0;
        #pragma unroll
        for (int r = 0; r < 4; ++r) {
            #pragma unroll
            for (int nt = 0; nt < 4; ++nt)
                po[(long)r * CC + nt * 16] = f2bf(acc[mt][nt][r]);
        }
        if (isv) {
            const long ng = (long)isxi * NS + n;   // multiple of 4 -> 8B aligned
            #pragma unroll
            for (int nt = 0; nt < 4; ++nt) {
                ushort4 o;
                o.x = f2bf(acc[mt][nt][0]); o.y = f2bf(acc[mt][nt][1]);
                o.z = f2bf(acc[mt][nt][2]); o.w = f2bf(acc[mt][nt][3]);
                *(ushort4*)(vvT + ((long)b * CC + j0 + nt * 16) * NS2 + ng) = o;
            }
        }
    }
}

// =================== input converts (fp32 -> bf16), merged ===================
__global__ void conv_in(const float* __restrict__ T, const float* __restrict__ x,
                        const float* __restrict__ xi,
                        unsigned short* __restrict__ Tb, unsigned short* __restrict__ xsb,
                        unsigned short* __restrict__ xisb)
{
    const int which = blockIdx.y;
    long i4 = ((long)blockIdx.x * 256 + threadIdx.x) * 4;
    const float* src; unsigned short* dst; long total; int rows, off, rpb;
    if (which == 0) { src = T;  dst = Tb;   total = (long)BB * NT * CC; rows = NT; off = 0;    rpb = NT; }
    else if (which == 1) { src = x;  dst = xsb;  total = (long)BB * NS * CC; rows = LX; off = TMPL; rpb = NS; }
    else            { src = xi; dst = xisb; total = (long)BB * NS * CC; rows = LX; off = TMPL; rpb = NS; }
    if (i4 >= total) return;
    int c   = (int)(i4 % CC);
    long rw = i4 / CC;
    int t   = (int)(rw % rpb);
    int b   = (int)(rw / rpb);
    const float4 f = *(const float4*)(src + ((long)b * rows + off + t) * CC + c);
    ushort4 o;
    o.x = f2bf(f.x); o.y = f2bf(f.y); o.z = f2bf(f.z); o.w = f2bf(f.w);
    *(ushort4*)(dst + i4) = o;
}

// fp32 W [CC][CC] -> bf16 W^T [CC][CC], 4 weights via blockIdx.z
__global__ void conv_wt4(const float* __restrict__ Wq, const float* __restrict__ Wk,
                         const float* __restrict__ Wv, const float* __restrict__ Wo,
                         unsigned short* __restrict__ WqT, unsigned short* __restrict__ WkT,
                         unsigned short* __restrict__ WvT, unsigned short* __restrict__ WoT)
{
    const float* W; unsigned short* WT;
    switch (blockIdx.z) {
        case 0: W = Wq; WT = WqT; break;
        case 1: W = Wk; WT = WkT; break;
        case 2: W = Wv; WT = WvT; break;
        default: W = Wo; WT = WoT; break;
    }
    __shared__ float tile[32][33];
    const int c0 = blockIdx.x * 32, r0 = blockIdx.y * 32;
    const int tx = threadIdx.x & 31, ty = threadIdx.x >> 5;
    #pragma unroll
    for (int i = 0; i < 4; ++i)
        tile[ty + 8 * i][tx] = W[(long)(r0 + ty + 8 * i) * CC + c0 + tx];
    __syncthreads();
    #pragma unroll
    for (int i = 0; i < 4; ++i)
        WT[(long)(c0 + ty + 8 * i) * CC + r0 + tx] = f2bf(tile[tx][ty + 8 * i]);
}

// =================== fused dual softmax + bf16 write + sign-pack ===================
__global__ void softmax_pack(const float* __restrict__ P, unsigned short* __restrict__ Pb,
                             u64* __restrict__ posm, u64* __restrict__ eqm)
{
    const long r = blockIdx.x;          // b*NT + t
    const float* p = P + r * NS2;
    const int tid = threadIdx.x;

    float a0 = p[tid], a1 = p[tid + 256], a2 = (tid < 64) ? p[tid + 512] : -1e30f;
    float m1 = block_max256(fmaxf(fmaxf(a0, a1), a2));
    float e0 = __expf(a0 - m1), e1 = __expf(a1 - m1), e2 = (tid < 64) ? __expf(a2 - m1) : 0.f;
    float s1 = block_sum256(e0 + e1 + e2);
    float i1 = 1.f / s1;
    e0 *= i1; e1 *= i1; e2 *= i1;

    const float* q = p + NS;
    float b0 = q[tid], b1 = q[tid + 256], b2 = (tid < 64) ? q[tid + 512] : -1e30f;
    float m2 = block_max256(fmaxf(fmaxf(b0, b1), b2));
    float f0 = __expf(b0 - m2), f1 = __expf(b1 - m2), f2v = (tid < 64) ? __expf(b2 - m2) : 0.f;
    float s2 = block_sum256(f0 + f1 + f2v);
    float i2 = 1.f / s2;
    f0 *= i2; f1 *= i2; f2v *= i2;

    unsigned short* ob = Pb + r * NS2;
    ob[tid] = f2bf(e0); ob[tid + 256] = f2bf(e1);
    if (tid < 64) ob[tid + 512] = f2bf(e2);
    ob[NS + tid] = f2bf(f0); ob[NS + tid + 256] = f2bf(f1);
    if (tid < 64) ob[NS + tid + 512] = f2bf(f2v);

    u64* pm = posm + r * 9;
    u64* em = eqm  + r * 9;
    const int wv = tid >> 6;
    float d0 = e0 - f0, d1 = e1 - f1, d2 = e2 - f2v;
    u64 P0 = __ballot(d0 > 0.f), E0 = __ballot(d0 == 0.f);
    if ((tid & 63) == 0) { pm[wv] = P0; em[wv] = E0; }
    u64 P1 = __ballot(d1 > 0.f), E1 = __ballot(d1 == 0.f);
    if ((tid & 63) == 0) { pm[4 + wv] = P1; em[4 + wv] = E1; }
    u64 P2 = __ballot(tid < 64 && d2 > 0.f), E2 = __ballot(tid < 64 && d2 == 0.f);
    if (tid == 0) { pm[8] = P2; em[8] = E2; }
}

// =================== fused count + x_s ===================
__global__ void xs_fused(const u64* __restrict__ posm, const u64* __restrict__ eqm,
                         const unsigned short* __restrict__ vvb, float* __restrict__ out)
{
    const int gid = blockIdx.x;          // b*NS + n
    const int b = gid / NS, n = gid - b * NS;
    const int tid = threadIdx.x;
    const int wsel = n >> 6, bit = n & 63;
    float ones = 0.f, eqc = 0.f;
    for (int t = tid; t < NT; t += 256) {
        long o = ((long)(b * NT + t)) * 9 + wsel;
        ones += (float)((posm[o] >> bit) & 1);
        eqc  += (float)((eqm[o]  >> bit) & 1);
    }
    ones = block_sum256(ones);
    eqc  = block_sum256(eqc);
    float rgb = ones * (1.f / NT), e = eqc * (1.f / NT);
    float c1 = rgb + e;
    float c2 = (1.f - rgb - e) + e;
    const unsigned* pv  = (const unsigned*)(vvb + ((long)b * NS2 + n) * CC);
    const unsigned* pvi = (const unsigned*)(vvb + ((long)b * NS2 + n + NS) * CC);
    float* po = out + ((long)b * NS + n) * CC;
    for (int idx = tid; idx < CC / 2; idx += 256) {
        unsigned a = pv[idx], bb = pvi[idx];
        float2 o2;
        o2.x = bf2f((unsigned short)(a & 0xFFFF)) * c1 + bf2f((unsigned short)(bb & 0xFFFF)) * c2;
        o2.y = bf2f((unsigned short)(a >> 16))    * c1 + bf2f((unsigned short)(bb >> 16))    * c2;
        *(float2*)(po + 2 * idx) = o2;
    }
}

// =================== T_new = LayerNorm(T + S2) ===================
__global__ void add_ln(const float* __restrict__ T, const float* __restrict__ S2,
                       const float* __restrict__ gamma, const float* __restrict__ beta,
                       float* __restrict__ out)
{
    const long r = blockIdx.x;            // b*NT + t
    const int tid = threadIdx.x;
    const float* tp = T  + r * CC;
    const float* sp = S2 + r * CC;
    float h[3];
    float sum = 0.f;
    #pragma unroll
    for (int i = 0; i < 3; ++i) {
        h[i] = tp[tid + 256 * i] + sp[tid + 256 * i];
        sum += h[i];
    }
    sum = block_sum256(sum);
    float mu = sum * (1.f / CC);
    float varp = 0.f;
    #pragma unroll
    for (int i = 0; i < 3; ++i) { float d = h[i] - mu; varp += d * d; }
    varp = block_sum256(varp);
    float inv = rsqrtf(varp * (1.f / CC) + LN_EPS);
    #pragma unroll
    for (int i = 0; i < 3; ++i) {
        int c = tid + 256 * i;
        out[r * CC + c] = (h[i] - mu) * inv * gamma[c] + beta[c];
    }
}

// =================== launch ===================
extern "C" void kernel_launch(void* const* d_in, const int* in_sizes, int n_in,
                              void* d_out, int out_size, void* d_ws, size_t ws_size,
                              hipStream_t stream) {
    const float* T     = (const float*)d_in[0];
    const float* x     = (const float*)d_in[1];
    const float* xi    = (const float*)d_in[2];
    const float* Wq    = (const float*)d_in[3];
    const float* Wk    = (const float*)d_in[4];
    const float* Wv    = (const float*)d_in[5];
    const float* Wout  = (const float*)d_in[6];
    const float* gamma = (const float*)d_in[7];
    const float* beta  = (const float*)d_in[8];
    float* out = (float*)d_out;

    // ---- workspace layout (bytes), ~288 MB ----
    const long B_T  = (long)BB * NT * CC * 2;         // 15.7 MB (Tb; later Sb)
    const long B_KK = (long)BB * NS2 * CC * 2;        // 56.6 MB
    const long B_WT = (long)CC * CC * 2;              // 1.18 MB each
    const long B_XS = (long)BB * NS * CC * 2;         // 28.3 MB each; pair overlaid by P fp32 (47.2 MB)
    const long B_PB = (long)BB * NT * NS2 * 2;        // 23.6 MB
    const long B_MK = (long)BB * NT * 9 * 8;          // 0.74 MB each

    char* cur = (char*)d_ws;
    unsigned short* Tb   = (unsigned short*)cur; cur += B_T;
    unsigned short* qb   = (unsigned short*)cur; cur += B_T;
    unsigned short* kkb  = (unsigned short*)cur; cur += B_KK;
    unsigned short* WqT  = (unsigned short*)cur; cur += B_WT;
    unsigned short* WkT  = (unsigned short*)cur; cur += B_WT;   // NOTE: WkT||WvT must stay
    unsigned short* WvT  = (unsigned short*)cur; cur += B_WT;   //       adjacent (proj_kv B operand)
    unsigned short* WoT  = (unsigned short*)cur; cur += B_WT;
    unsigned short* vvb  = (unsigned short*)cur; cur += B_KK;
    unsigned short* vvT  = (unsigned short*)cur; cur += B_KK;
    unsigned short* xsb  = (unsigned short*)cur;                // NOTE: xsb||xisb contiguous
    unsigned short* xisb = xsb + (long)BB * NS * CC;  cur += 2 * B_XS;
    unsigned short* Pb   = (unsigned short*)cur; cur += B_PB;
    u64* posm            = (u64*)cur; cur += B_MK;
    u64* eqm             = (u64*)cur; cur += B_MK;
    if ((size_t)(cur - (char*)d_ws) > ws_size) return;

    float* P  = (float*)xsb;    // xsb/xisb dead after projections; 47.2 <= 56.6 MB
    unsigned short* Sb = Tb;    // Tb dead after q GEMM
    float* S2 = (float*)vvb;    // vvb dead after xs_fused; 31.5 <= 56.6 MB

    const float scale = 1.0f / sqrtf((float)CC);
    dim3 blk(256);

    // 1. converts (2 dispatches)
    conv_in<<<dim3((BB * NS * CC) / 1024, 3), blk, 0, stream>>>(T, x, xi, Tb, xsb, xisb);
    conv_wt4<<<dim3(CC / 32, CC / 32, 4), blk, 0, stream>>>(Wq, Wk, Wv, Wout, WqT, WkT, WvT, WoT);

    // 2. merged KV projections as ONE flat GEMM: M=36864, N=1536, K=768
    //    3456 blocks = 8 XCD chunks x 432, XCD-swizzled inside the kernel.
    //    v-half dual-writes vvT (transposed) -> no separate trans_vv pass.
    proj_kv<<<dim3(((2 * CC) / 128) * ((2 * BB * NS) / 128)), blk, 0, stream>>>(
        (const short*)xsb, (const short*)WkT, kkb, vvb, vvT);

    // 3. q = T @ Wq  (flat across batch: M = B*NT = 10240; 480 blocks = 8 x 60)
    gemm128<false><<<dim3((CC / 128) * ((BB * NT) / 128)), blk, 0, stream>>>(
        (const short*)Tb, (const short*)WqT, qb, CC, CC, CC / 128, 1.f);

    // 4. logits (fp32): P = scale * q @ [k|ki]^T  (per-batch B operand, M=320 -> gemm64)
    gemm64<true><<<dim3(NS2 / 128, NT / 64, BB), blk, 0, stream>>>(
        (const short*)qb, (const short*)kkb, P, NS2, CC,
        (long)NT * CC, (long)NS2 * CC, (long)NT * NS2, scale);

    // 5. dual softmax + bf16 P + sign masks
    softmax_pack<<<BB * NT, blk, 0, stream>>>(P, Pb, posm, eqm);

    // 6. fused count + x_s -> d_out[0 : B*NS*CC]
    xs_fused<<<BB * NS, blk, 0, stream>>>(posm, eqm, vvb, out);

    // 7. S = [aw|awi] @ [v;vi]   (bf16, K=1152, per-batch B operand -> gemm64)
    gemm64<false><<<dim3(CC / 128, NT / 64, BB), blk, 0, stream>>>(
        (const short*)Pb, (const short*)vvT, Sb, CC, NS2,
        (long)NT * NS2, (long)CC * NS2, (long)NT * CC, 1.f);

    // 8. S2 = S @ Wout  (fp32, flat: M = B*NT = 10240)
    gemm128<true><<<dim3((CC / 128) * ((BB * NT) / 128)), blk, 0, stream>>>(
        (const short*)Sb, (const short*)WoT, S2, CC, CC, CC / 128, 1.f);

    // 9. T_new = LN(T + S2) -> d_out tail
    add_ln<<<BB * NT, blk, 0, stream>>>(T, S2, gamma, beta, out + (long)BB * NS * CC);
}

// Round 5
// 547.730 us; speedup vs baseline: 1.2120x; 1.1164x over previous
//
#include <hip/hip_runtime.h>

// Problem constants
#define BB   32
#define NT   320      // T rows per batch (= 5*64)
#define LX   704
#define TMPL 128
#define NS   576      // LX - TMPL (= 9*64)
#define CC   768
#define NS2  1152     // 2*NS
#define LN_EPS 1e-5f

typedef __attribute__((ext_vector_type(8))) short short8;   // 8 bf16 (4 VGPRs)
typedef __attribute__((ext_vector_type(4))) float f32x4;
typedef unsigned long long u64;

typedef __attribute__((address_space(3))) void as3_void;
typedef __attribute__((address_space(1))) void as1_void;
#define GLDS16(g, l) __builtin_amdgcn_global_load_lds((const as1_void*)(g), (as3_void*)(l), 16, 0, 0)

__device__ __forceinline__ unsigned short f2bf(float f) {
    union { float f; unsigned u; } v; v.f = f;
    unsigned r = v.u + 0x7FFFu + ((v.u >> 16) & 1u);   // RNE
    return (unsigned short)(r >> 16);
}
__device__ __forceinline__ float bf2f(unsigned short h) {
    union { unsigned u; float f; } v; v.u = ((unsigned)h) << 16;
    return v.f;
}

// XCD-aware bijective swizzle of a linear workgroup id (8 XCDs; requires nwg % 8 == 0).
// Each XCD gets a contiguous chunk of work-ids -> neighbor tiles / whole batches
// share that XCD's L2. [T1, learn_hip m192/m204]
__device__ __forceinline__ int xcd_swz(int orig, int nwg) {
    int cpx = nwg >> 3;
    return (orig & 7) * cpx + (orig >> 3);
}

// ---------------- block reductions (blockDim == 256) ----------------
__device__ __forceinline__ float block_sum256(float v) {
    __shared__ float sm[4];
    #pragma unroll
    for (int o = 32; o > 0; o >>= 1) v += __shfl_down(v, o, 64);
    __syncthreads();
    if ((threadIdx.x & 63) == 0) sm[threadIdx.x >> 6] = v;
    __syncthreads();
    return sm[0] + sm[1] + sm[2] + sm[3];
}
__device__ __forceinline__ float block_max256(float v) {
    __shared__ float sm[4];
    #pragma unroll
    for (int o = 32; o > 0; o >>= 1) v = fmaxf(v, __shfl_down(v, o, 64));
    __syncthreads();
    if ((threadIdx.x & 63) == 0) sm[threadIdx.x >> 6] = v;
    __syncthreads();
    return fmaxf(fmaxf(sm[0], sm[1]), fmaxf(sm[2], sm[3]));
}

// =================== bf16 MFMA GEMM core: BM=64, BN=128, BK=32 ===================
// (per-batch logits / PV GEMMs where M=320 is not a 128-multiple)
// C(M x N) = alpha * A(M x K, row-major bf16) @ Bt(N x K, row-major bf16)^T
// 256 threads = 4 waves in 2x2; wave tile 32x64 (2x4 MFMA 16x16x32).
// LDS chunk-swizzle: global 16B k-chunk g lives at position p = g ^ ((row>>1)&3)
template<bool F32OUT>
__device__ __forceinline__ void gemm64_core(const short* __restrict__ Ab,
                                            const short* __restrict__ Bb,
                                            void* __restrict__ Cb,
                                            int m0, int n0,
                                            int N, int K, float alpha)
{
    __shared__ short As[64 * 32];    // 4 KB
    __shared__ short Bs[128 * 32];   // 8 KB
    const int tid  = threadIdx.x;
    const int lane = tid & 63;
    const int w    = tid >> 6;
    const int wr   = (w >> 1) * 32;   // wave row in tile
    const int wc   = (w & 1) * 64;    // wave col in tile

    const int srow = tid >> 2;
    const int g    = ((tid & 3) ^ ((srow >> 1) & 3)) * 8;
    const short* gA  = Ab + (long)(m0 + srow) * K + g;
    const short* gB0 = Bb + (long)(n0 + srow) * K + g;
    const short* gB1 = gB0 + (long)64 * K;
    short* lA  = As + tid * 8;
    short* lB0 = Bs + tid * 8;
    short* lB1 = Bs + 2048 + tid * 8;

    const int fl = lane & 15;         // m/n within 16-tile
    const int ch = lane >> 4;         // k-chunk index 0..3

    f32x4 acc[2][4] = {};

    for (int k0 = 0; k0 < K; k0 += 32) {
        GLDS16(gA  + k0, lA);
        GLDS16(gB0 + k0, lB0);
        GLDS16(gB1 + k0, lB1);
        __syncthreads();

        short8 af[2], bfv[4];
        #pragma unroll
        for (int mt = 0; mt < 2; ++mt) {
            int row = wr + mt * 16 + fl;
            af[mt] = *(const short8*)(As + row * 32 + ((ch ^ ((row >> 1) & 3)) * 8));
        }
        #pragma unroll
        for (int nt = 0; nt < 4; ++nt) {
            int row = wc + nt * 16 + fl;
            bfv[nt] = *(const short8*)(Bs + row * 32 + ((ch ^ ((row >> 1) & 3)) * 8));
        }
        #pragma unroll
        for (int mt = 0; mt < 2; ++mt)
            #pragma unroll
            for (int nt = 0; nt < 4; ++nt)
                acc[mt][nt] = __builtin_amdgcn_mfma_f32_16x16x32_bf16(
                    af[mt], bfv[nt], acc[mt][nt], 0, 0, 0);
        __syncthreads();
    }

    float* Cf = (float*)Cb;
    unsigned short* Ch = (unsigned short*)Cb;
    const int rq = (lane >> 4) * 4;
    #pragma unroll
    for (int mt = 0; mt < 2; ++mt) {
        #pragma unroll
        for (int r = 0; r < 4; ++r) {
            long ro = (long)(m0 + wr + mt * 16 + rq + r) * N + n0 + wc + fl;
            #pragma unroll
            for (int nt = 0; nt < 4; ++nt) {
                float val = acc[mt][nt][r] * alpha;
                if (F32OUT) Cf[ro + nt * 16] = val;
                else        Ch[ro + nt * 16] = f2bf(val);
            }
        }
    }
}

// batched gemm64 with 1D grid + XCD swizzle: each XCD owns contiguous whole-batch
// chunks so the per-batch A/B panels (~2.5 MB) stay in its private L2.
// grid = BB * ntx * nty (must be % 8 == 0). n-tile fastest within a batch.
template<bool F32OUT>
__global__ __launch_bounds__(256) void gemm64x(
    const short* __restrict__ A, const short* __restrict__ Bt, void* __restrict__ C,
    int N, int K, long sA, long sB, long sC, float alpha, int ntx, int nty)
{
    const int wg  = xcd_swz(blockIdx.x, gridDim.x);
    const int per = ntx * nty;
    const int b   = wg / per;
    const int rem = wg - b * per;
    const int n0  = (rem % ntx) * 128;
    const int m0  = (rem / ntx) * 64;
    void* Cb = F32OUT ? (void*)((float*)C + (long)b * sC)
                      : (void*)((unsigned short*)C + (long)b * sC);
    gemm64_core<F32OUT>(A + (long)b * sA, Bt + (long)b * sB, Cb, m0, n0, N, K, alpha);
}

// =================== bf16 MFMA GEMM core: BM=128, BN=128, BK=32 (m97 structure) ===================
// 256 threads = 4 waves in 2x2; wave tile 64x64 (4x4 MFMA 16x16x32).
// Ab/Bb must already point at the tile origin (A + m0*K, Bt + n0*K). K % 32 == 0.
__device__ __forceinline__ void gemm128_acc(const short* __restrict__ Ab,
                                            const short* __restrict__ Bb,
                                            int K, f32x4 acc[4][4])
{
    __shared__ short As[128 * 32];   // 8 KB
    __shared__ short Bs[128 * 32];   // 8 KB
    const int tid  = threadIdx.x;
    const int lane = tid & 63;
    const int w    = tid >> 6;
    const int wr   = (w >> 1) * 64;
    const int wc   = (w & 1) * 64;

    const int srow = tid >> 2;                       // 0..63
    const int g    = ((tid & 3) ^ ((srow >> 1) & 3)) * 8;
    const short* gA0 = Ab + (long)srow * K + g;
    const short* gA1 = gA0 + (long)64 * K;
    const short* gB0 = Bb + (long)srow * K + g;
    const short* gB1 = gB0 + (long)64 * K;
    short* lA0 = As + tid * 8;
    short* lA1 = As + 2048 + tid * 8;
    short* lB0 = Bs + tid * 8;
    short* lB1 = Bs + 2048 + tid * 8;

    const int fl = lane & 15;
    const int ch = lane >> 4;

    for (int k0 = 0; k0 < K; k0 += 32) {
        GLDS16(gA0 + k0, lA0);
        GLDS16(gA1 + k0, lA1);
        GLDS16(gB0 + k0, lB0);
        GLDS16(gB1 + k0, lB1);
        __syncthreads();

        short8 af[4], bfv[4];
        #pragma unroll
        for (int mt = 0; mt < 4; ++mt) {
            int row = wr + mt * 16 + fl;
            af[mt] = *(const short8*)(As + row * 32 + ((ch ^ ((row >> 1) & 3)) * 8));
        }
        #pragma unroll
        for (int nt = 0; nt < 4; ++nt) {
            int row = wc + nt * 16 + fl;
            bfv[nt] = *(const short8*)(Bs + row * 32 + ((ch ^ ((row >> 1) & 3)) * 8));
        }
        #pragma unroll
        for (int mt = 0; mt < 4; ++mt)
            #pragma unroll
            for (int nt = 0; nt < 4; ++nt)
                acc[mt][nt] = __builtin_amdgcn_mfma_f32_16x16x32_bf16(
                    af[mt], bfv[nt], acc[mt][nt], 0, 0, 0);
        __syncthreads();
    }
}

// flat GEMM, M % 128 == 0, N % 128 == 0: C[M][N] = alpha * A[M][K] @ Bt[N][K]^T
// 1D grid, n-tile fastest after XCD swizzle.
// launch_bounds(256,4): force <=128 total regs/wave -> 4 waves/SIMD (vs 3 at 136).
template<bool F32OUT>
__global__ __launch_bounds__(256, 4) void gemm128(
    const short* __restrict__ A, const short* __restrict__ Bt, void* __restrict__ C,
    int N, int K, int ntiles_n, float alpha)
{
    const int wg = xcd_swz(blockIdx.x, gridDim.x);
    const int n0 = (wg % ntiles_n) * 128;
    const int m0 = (wg / ntiles_n) * 128;
    f32x4 acc[4][4] = {};
    gemm128_acc(A + (long)m0 * K, Bt + (long)n0 * K, K, acc);

    const int tid = threadIdx.x, lane = tid & 63, w = tid >> 6;
    const int wr = (w >> 1) * 64, wc = (w & 1) * 64;
    const int fl = lane & 15, rq = (lane >> 4) * 4;
    float* Cf = (float*)C;
    unsigned short* Ch = (unsigned short*)C;
    #pragma unroll
    for (int mt = 0; mt < 4; ++mt) {
        #pragma unroll
        for (int r = 0; r < 4; ++r) {
            long ro = (long)(m0 + wr + mt * 16 + rq + r) * N + n0 + wc + fl;
            #pragma unroll
            for (int nt = 0; nt < 4; ++nt) {
                float val = acc[mt][nt][r] * alpha;
                if (F32OUT) Cf[ro + nt * 16] = val;
                else        Ch[ro + nt * 16] = f2bf(val);
            }
        }
    }
}

// =================== merged KV projection as ONE flat 128^2 GEMM ===================
// A = xsb||xisb viewed as [2*B*NS = 36864][CC]  (contiguous in workspace)
// Bt = WkT||WvT viewed as [2*CC = 1536][CC]     (contiguous in workspace)
// scatter epilogue: row -> (xs/xi, b, n), col -> (k-buf / v-buf)
// v-half additionally dual-writes the TRANSPOSED layout vvT[b][c][n_global]
// (each lane's 4 acc regs = 4 consecutive n at one col -> packed ushort4 store),
// which eliminates the separate trans_vv kernel.
// XCD swizzle: 3456 blocks = 8 x 432.
#define PKV_NT 12      // n-tiles = 1536/128
__global__ __launch_bounds__(256, 4) void proj_kv(
    const short* __restrict__ X, const short* __restrict__ WkvT,
    unsigned short* __restrict__ kkb, unsigned short* __restrict__ vvb,
    unsigned short* __restrict__ vvT)
{
    const int wg = xcd_swz(blockIdx.x, gridDim.x);
    const int n0 = (wg % PKV_NT) * 128;     // 0..1408
    const int m0 = (wg / PKV_NT) * 128;     // 0..36736
    f32x4 acc[4][4] = {};
    gemm128_acc(X + (long)m0 * CC, WkvT + (long)n0 * CC, CC, acc);

    const int tid = threadIdx.x, lane = tid & 63, w = tid >> 6;
    const int wr = (w >> 1) * 64, wc = (w & 1) * 64;
    const int fl = lane & 15, rq = (lane >> 4) * 4;

    const bool isv = (n0 >= CC);
    unsigned short* base = isv ? vvb : kkb;
    const int j0 = (isv ? n0 - CC : n0) + wc + fl;

    #pragma unroll
    for (int mt = 0; mt < 4; ++mt) {
        // rows rq..rq+3 stay within one (b, isxi) group: 16 | NS and 16 | BB*NS.
        const int row0 = m0 + wr + mt * 16 + rq;
        const int isxi = (row0 >= BB * NS) ? 1 : 0;
        const int r2   = row0 - isxi * (BB * NS);
        const int b    = r2 / NS;
        const int n    = r2 - b * NS;
        unsigned short* po = base + (long)b * NS2 * CC
                                  + (long)isxi * NS * CC
                                  + (long)n * CC + j0;
        #pragma unroll
        for (int r = 0; r < 4; ++r) {
            #pragma unroll
            for (int nt = 0; nt < 4; ++nt)
                po[(long)r * CC + nt * 16] = f2bf(acc[mt][nt][r]);
        }
        if (isv) {
            const long ng = (long)isxi * NS + n;   // multiple of 4 -> 8B aligned
            #pragma unroll
            for (int nt = 0; nt < 4; ++nt) {
                ushort4 o;
                o.x = f2bf(acc[mt][nt][0]); o.y = f2bf(acc[mt][nt][1]);
                o.z = f2bf(acc[mt][nt][2]); o.w = f2bf(acc[mt][nt][3]);
                *(ushort4*)(vvT + ((long)b * CC + j0 + nt * 16) * NS2 + ng) = o;
            }
        }
    }
}

// =================== input converts (fp32 -> bf16), merged ===================
__global__ void conv_in(const float* __restrict__ T, const float* __restrict__ x,
                        const float* __restrict__ xi,
                        unsigned short* __restrict__ Tb, unsigned short* __restrict__ xsb,
                        unsigned short* __restrict__ xisb)
{
    const int which = blockIdx.y;
    long i4 = ((long)blockIdx.x * 256 + threadIdx.x) * 4;
    const float* src; unsigned short* dst; long total; int rows, off, rpb;
    if (which == 0) { src = T;  dst = Tb;   total = (long)BB * NT * CC; rows = NT; off = 0;    rpb = NT; }
    else if (which == 1) { src = x;  dst = xsb;  total = (long)BB * NS * CC; rows = LX; off = TMPL; rpb = NS; }
    else            { src = xi; dst = xisb; total = (long)BB * NS * CC; rows = LX; off = TMPL; rpb = NS; }
    if (i4 >= total) return;
    int c   = (int)(i4 % CC);
    long rw = i4 / CC;
    int t   = (int)(rw % rpb);
    int b   = (int)(rw / rpb);
    const float4 f = *(const float4*)(src + ((long)b * rows + off + t) * CC + c);
    ushort4 o;
    o.x = f2bf(f.x); o.y = f2bf(f.y); o.z = f2bf(f.z); o.w = f2bf(f.w);
    *(ushort4*)(dst + i4) = o;
}

// fp32 W [CC][CC] -> bf16 W^T [CC][CC], 4 weights via blockIdx.z
__global__ void conv_wt4(const float* __restrict__ Wq, const float* __restrict__ Wk,
                         const float* __restrict__ Wv, const float* __restrict__ Wo,
                         unsigned short* __restrict__ WqT, unsigned short* __restrict__ WkT,
                         unsigned short* __restrict__ WvT, unsigned short* __restrict__ WoT)
{
    const float* W; unsigned short* WT;
    switch (blockIdx.z) {
        case 0: W = Wq; WT = WqT; break;
        case 1: W = Wk; WT = WkT; break;
        case 2: W = Wv; WT = WvT; break;
        default: W = Wo; WT = WoT; break;
    }
    __shared__ float tile[32][33];
    const int c0 = blockIdx.x * 32, r0 = blockIdx.y * 32;
    const int tx = threadIdx.x & 31, ty = threadIdx.x >> 5;
    #pragma unroll
    for (int i = 0; i < 4; ++i)
        tile[ty + 8 * i][tx] = W[(long)(r0 + ty + 8 * i) * CC + c0 + tx];
    __syncthreads();
    #pragma unroll
    for (int i = 0; i < 4; ++i)
        WT[(long)(c0 + ty + 8 * i) * CC + r0 + tx] = f2bf(tile[tx][ty + 8 * i]);
}

// =================== fused dual softmax + bf16 write + sign-pack ===================
__global__ void softmax_pack(const float* __restrict__ P, unsigned short* __restrict__ Pb,
                             u64* __restrict__ posm, u64* __restrict__ eqm)
{
    const long r = blockIdx.x;          // b*NT + t
    const float* p = P + r * NS2;
    const int tid = threadIdx.x;

    float a0 = p[tid], a1 = p[tid + 256], a2 = (tid < 64) ? p[tid + 512] : -1e30f;
    float m1 = block_max256(fmaxf(fmaxf(a0, a1), a2));
    float e0 = __expf(a0 - m1), e1 = __expf(a1 - m1), e2 = (tid < 64) ? __expf(a2 - m1) : 0.f;
    float s1 = block_sum256(e0 + e1 + e2);
    float i1 = 1.f / s1;
    e0 *= i1; e1 *= i1; e2 *= i1;

    const float* q = p + NS;
    float b0 = q[tid], b1 = q[tid + 256], b2 = (tid < 64) ? q[tid + 512] : -1e30f;
    float m2 = block_max256(fmaxf(fmaxf(b0, b1), b2));
    float f0 = __expf(b0 - m2), f1 = __expf(b1 - m2), f2v = (tid < 64) ? __expf(b2 - m2) : 0.f;
    float s2 = block_sum256(f0 + f1 + f2v);
    float i2 = 1.f / s2;
    f0 *= i2; f1 *= i2; f2v *= i2;

    unsigned short* ob = Pb + r * NS2;
    ob[tid] = f2bf(e0); ob[tid + 256] = f2bf(e1);
    if (tid < 64) ob[tid + 512] = f2bf(e2);
    ob[NS + tid] = f2bf(f0); ob[NS + tid + 256] = f2bf(f1);
    if (tid < 64) ob[NS + tid + 512] = f2bf(f2v);

    u64* pm = posm + r * 9;
    u64* em = eqm  + r * 9;
    const int wv = tid >> 6;
    float d0 = e0 - f0, d1 = e1 - f1, d2 = e2 - f2v;
    u64 P0 = __ballot(d0 > 0.f), E0 = __ballot(d0 == 0.f);
    if ((tid & 63) == 0) { pm[wv] = P0; em[wv] = E0; }
    u64 P1 = __ballot(d1 > 0.f), E1 = __ballot(d1 == 0.f);
    if ((tid & 63) == 0) { pm[4 + wv] = P1; em[4 + wv] = E1; }
    u64 P2 = __ballot(tid < 64 && d2 > 0.f), E2 = __ballot(tid < 64 && d2 == 0.f);
    if (tid == 0) { pm[8] = P2; em[8] = E2; }
}

// =================== fused count + x_s ===================
__global__ void xs_fused(const u64* __restrict__ posm, const u64* __restrict__ eqm,
                         const unsigned short* __restrict__ vvb, float* __restrict__ out)
{
    const int gid = blockIdx.x;          // b*NS + n
    const int b = gid / NS, n = gid - b * NS;
    const int tid = threadIdx.x;
    const int wsel = n >> 6, bit = n & 63;
    float ones = 0.f, eqc = 0.f;
    for (int t = tid; t < NT; t += 256) {
        long o = ((long)(b * NT + t)) * 9 + wsel;
        ones += (float)((posm[o] >> bit) & 1);
        eqc  += (float)((eqm[o]  >> bit) & 1);
    }
    ones = block_sum256(ones);
    eqc  = block_sum256(eqc);
    float rgb = ones * (1.f / NT), e = eqc * (1.f / NT);
    float c1 = rgb + e;
    float c2 = (1.f - rgb - e) + e;
    const unsigned* pv  = (const unsigned*)(vvb + ((long)b * NS2 + n) * CC);
    const unsigned* pvi = (const unsigned*)(vvb + ((long)b * NS2 + n + NS) * CC);
    float* po = out + ((long)b * NS + n) * CC;
    for (int idx = tid; idx < CC / 2; idx += 256) {
        unsigned a = pv[idx], bb = pvi[idx];
        float2 o2;
        o2.x = bf2f((unsigned short)(a & 0xFFFF)) * c1 + bf2f((unsigned short)(bb & 0xFFFF)) * c2;
        o2.y = bf2f((unsigned short)(a >> 16))    * c1 + bf2f((unsigned short)(bb >> 16))    * c2;
        *(float2*)(po + 2 * idx) = o2;
    }
}

// =================== T_new = LayerNorm(T + S2) ===================
__global__ void add_ln(const float* __restrict__ T, const float* __restrict__ S2,
                       const float* __restrict__ gamma, const float* __restrict__ beta,
                       float* __restrict__ out)
{
    const long r = blockIdx.x;            // b*NT + t
    const int tid = threadIdx.x;
    const float* tp = T  + r * CC;
    const float* sp = S2 + r * CC;
    float h[3];
    float sum = 0.f;
    #pragma unroll
    for (int i = 0; i < 3; ++i) {
        h[i] = tp[tid + 256 * i] + sp[tid + 256 * i];
        sum += h[i];
    }
    sum = block_sum256(sum);
    float mu = sum * (1.f / CC);
    float varp = 0.f;
    #pragma unroll
    for (int i = 0; i < 3; ++i) { float d = h[i] - mu; varp += d * d; }
    varp = block_sum256(varp);
    float inv = rsqrtf(varp * (1.f / CC) + LN_EPS);
    #pragma unroll
    for (int i = 0; i < 3; ++i) {
        int c = tid + 256 * i;
        out[r * CC + c] = (h[i] - mu) * inv * gamma[c] + beta[c];
    }
}

// =================== launch ===================
extern "C" void kernel_launch(void* const* d_in, const int* in_sizes, int n_in,
                              void* d_out, int out_size, void* d_ws, size_t ws_size,
                              hipStream_t stream) {
    const float* T     = (const float*)d_in[0];
    const float* x     = (const float*)d_in[1];
    const float* xi    = (const float*)d_in[2];
    const float* Wq    = (const float*)d_in[3];
    const float* Wk    = (const float*)d_in[4];
    const float* Wv    = (const float*)d_in[5];
    const float* Wout  = (const float*)d_in[6];
    const float* gamma = (const float*)d_in[7];
    const float* beta  = (const float*)d_in[8];
    float* out = (float*)d_out;

    // ---- workspace layout (bytes), ~288 MB ----
    const long B_T  = (long)BB * NT * CC * 2;         // 15.7 MB (Tb; later Sb)
    const long B_KK = (long)BB * NS2 * CC * 2;        // 56.6 MB
    const long B_WT = (long)CC * CC * 2;              // 1.18 MB each
    const long B_XS = (long)BB * NS * CC * 2;         // 28.3 MB each; pair overlaid by P fp32 (47.2 MB)
    const long B_PB = (long)BB * NT * NS2 * 2;        // 23.6 MB
    const long B_MK = (long)BB * NT * 9 * 8;          // 0.74 MB each

    char* cur = (char*)d_ws;
    unsigned short* Tb   = (unsigned short*)cur; cur += B_T;
    unsigned short* qb   = (unsigned short*)cur; cur += B_T;
    unsigned short* kkb  = (unsigned short*)cur; cur += B_KK;
    unsigned short* WqT  = (unsigned short*)cur; cur += B_WT;
    unsigned short* WkT  = (unsigned short*)cur; cur += B_WT;   // NOTE: WkT||WvT must stay
    unsigned short* WvT  = (unsigned short*)cur; cur += B_WT;   //       adjacent (proj_kv B operand)
    unsigned short* WoT  = (unsigned short*)cur; cur += B_WT;
    unsigned short* vvb  = (unsigned short*)cur; cur += B_KK;
    unsigned short* vvT  = (unsigned short*)cur; cur += B_KK;
    unsigned short* xsb  = (unsigned short*)cur;                // NOTE: xsb||xisb contiguous
    unsigned short* xisb = xsb + (long)BB * NS * CC;  cur += 2 * B_XS;
    unsigned short* Pb   = (unsigned short*)cur; cur += B_PB;
    u64* posm            = (u64*)cur; cur += B_MK;
    u64* eqm             = (u64*)cur; cur += B_MK;
    if ((size_t)(cur - (char*)d_ws) > ws_size) return;

    float* P  = (float*)xsb;    // xsb/xisb dead after projections; 47.2 <= 56.6 MB
    unsigned short* Sb = Tb;    // Tb dead after q GEMM
    float* S2 = (float*)vvb;    // vvb dead after xs_fused; 31.5 <= 56.6 MB

    const float scale = 1.0f / sqrtf((float)CC);
    dim3 blk(256);

    // 1. converts (2 dispatches)
    conv_in<<<dim3((BB * NS * CC) / 1024, 3), blk, 0, stream>>>(T, x, xi, Tb, xsb, xisb);
    conv_wt4<<<dim3(CC / 32, CC / 32, 4), blk, 0, stream>>>(Wq, Wk, Wv, Wout, WqT, WkT, WvT, WoT);

    // 2. merged KV projections as ONE flat GEMM: M=36864, N=1536, K=768
    //    3456 blocks = 8 XCD chunks x 432, XCD-swizzled inside the kernel.
    //    v-half dual-writes vvT (transposed) -> no separate trans_vv pass.
    proj_kv<<<dim3(((2 * CC) / 128) * ((2 * BB * NS) / 128)), blk, 0, stream>>>(
        (const short*)xsb, (const short*)WkT, kkb, vvb, vvT);

    // 3. q = T @ Wq  (flat across batch: M = B*NT = 10240; 480 blocks = 8 x 60)
    gemm128<false><<<dim3((CC / 128) * ((BB * NT) / 128)), blk, 0, stream>>>(
        (const short*)Tb, (const short*)WqT, qb, CC, CC, CC / 128, 1.f);

    // 4. logits (fp32): P = scale * q @ [k|ki]^T
    //    1440 blocks = 8 XCDs x 180 (4 whole batches per XCD; 2.3 MB/batch in L2)
    gemm64x<true><<<dim3(BB * (NS2 / 128) * (NT / 64)), blk, 0, stream>>>(
        (const short*)qb, (const short*)kkb, P, NS2, CC,
        (long)NT * CC, (long)NS2 * CC, (long)NT * NS2, scale, NS2 / 128, NT / 64);

    // 5. dual softmax + bf16 P + sign masks
    softmax_pack<<<BB * NT, blk, 0, stream>>>(P, Pb, posm, eqm);

    // 6. fused count + x_s -> d_out[0 : B*NS*CC]
    xs_fused<<<BB * NS, blk, 0, stream>>>(posm, eqm, vvb, out);

    // 7. S = [aw|awi] @ [v;vi]   (bf16, K=1152)
    //    960 blocks = 8 XCDs x 120 (4 whole batches per XCD; 2.5 MB/batch in L2)
    gemm64x<false><<<dim3(BB * (CC / 128) * (NT / 64)), blk, 0, stream>>>(
        (const short*)Pb, (const short*)vvT, Sb, CC, NS2,
        (long)NT * NS2, (long)CC * NS2, (long)NT * CC, 1.f, CC / 128, NT / 64);

    // 8. S2 = S @ Wout  (fp32, flat: M = B*NT = 10240)
    gemm128<true><<<dim3((CC / 128) * ((BB * NT) / 128)), blk, 0, stream>>>(
        (const short*)Sb, (const short*)WoT, S2, CC, CC, CC / 128, 1.f);

    // 9. T_new = LN(T + S2) -> d_out tail
    add_ln<<<BB * NT, blk, 0, stream>>>(T, S2, gamma, beta, out + (long)BB * NS * CC);
}

// Round 6
// 534.390 us; speedup vs baseline: 1.2423x; 1.0250x over previous
//
#include <hip/hip_runtime.h>

// Problem constants
#define BB   32
#define NT   320      // T rows per batch (= 5*64)
#define LX   704
#define TMPL 128
#define NS   576      // LX - TMPL (= 9*64)
#define CC   768
#define NS2  1152     // 2*NS
#define LN_EPS 1e-5f

typedef __attribute__((ext_vector_type(8))) short short8;   // 8 bf16 (4 VGPRs)
typedef __attribute__((ext_vector_type(4))) float f32x4;
typedef unsigned long long u64;

typedef __attribute__((address_space(3))) void as3_void;
typedef __attribute__((address_space(1))) void as1_void;
#define GLDS16(g, l) __builtin_amdgcn_global_load_lds((const as1_void*)(g), (as3_void*)(l), 16, 0, 0)

__device__ __forceinline__ unsigned short f2bf(float f) {
    union { float f; unsigned u; } v; v.f = f;
    unsigned r = v.u + 0x7FFFu + ((v.u >> 16) & 1u);   // RNE
    return (unsigned short)(r >> 16);
}
__device__ __forceinline__ float bf2f(unsigned short h) {
    union { unsigned u; float f; } v; v.u = ((unsigned)h) << 16;
    return v.f;
}

// XCD-aware bijective swizzle of a linear workgroup id (8 XCDs; requires nwg % 8 == 0).
// Each XCD gets a contiguous chunk of work-ids -> neighbor tiles / whole batches
// share that XCD's L2. [T1, learn_hip m192/m204]
__device__ __forceinline__ int xcd_swz(int orig, int nwg) {
    int cpx = nwg >> 3;
    return (orig & 7) * cpx + (orig >> 3);
}

// ---------------- block reductions (blockDim == 256) ----------------
__device__ __forceinline__ float block_sum256(float v) {
    __shared__ float sm[4];
    #pragma unroll
    for (int o = 32; o > 0; o >>= 1) v += __shfl_down(v, o, 64);
    __syncthreads();
    if ((threadIdx.x & 63) == 0) sm[threadIdx.x >> 6] = v;
    __syncthreads();
    return sm[0] + sm[1] + sm[2] + sm[3];
}

// =================== bf16 MFMA GEMM core: BM=64, BN=128, BK=32 ===================
// (per-batch logits / PV GEMMs where M=320 is not a 128-multiple)
// C(M x N) = alpha * A(M x K, row-major bf16) @ Bt(N x K, row-major bf16)^T
// 256 threads = 4 waves in 2x2; wave tile 32x64 (2x4 MFMA 16x16x32).
// LDS chunk-swizzle: global 16B k-chunk g lives at position p = g ^ ((row>>1)&3)
template<bool F32OUT>
__device__ __forceinline__ void gemm64_core(const short* __restrict__ Ab,
                                            const short* __restrict__ Bb,
                                            void* __restrict__ Cb,
                                            int m0, int n0,
                                            int N, int K, float alpha)
{
    __shared__ short As[64 * 32];    // 4 KB
    __shared__ short Bs[128 * 32];   // 8 KB
    const int tid  = threadIdx.x;
    const int lane = tid & 63;
    const int w    = tid >> 6;
    const int wr   = (w >> 1) * 32;   // wave row in tile
    const int wc   = (w & 1) * 64;    // wave col in tile

    const int srow = tid >> 2;
    const int g    = ((tid & 3) ^ ((srow >> 1) & 3)) * 8;
    const short* gA  = Ab + (long)(m0 + srow) * K + g;
    const short* gB0 = Bb + (long)(n0 + srow) * K + g;
    const short* gB1 = gB0 + (long)64 * K;
    short* lA  = As + tid * 8;
    short* lB0 = Bs + tid * 8;
    short* lB1 = Bs + 2048 + tid * 8;

    const int fl = lane & 15;         // m/n within 16-tile
    const int ch = lane >> 4;         // k-chunk index 0..3

    f32x4 acc[2][4] = {};

    for (int k0 = 0; k0 < K; k0 += 32) {
        GLDS16(gA  + k0, lA);
        GLDS16(gB0 + k0, lB0);
        GLDS16(gB1 + k0, lB1);
        __syncthreads();

        short8 af[2], bfv[4];
        #pragma unroll
        for (int mt = 0; mt < 2; ++mt) {
            int row = wr + mt * 16 + fl;
            af[mt] = *(const short8*)(As + row * 32 + ((ch ^ ((row >> 1) & 3)) * 8));
        }
        #pragma unroll
        for (int nt = 0; nt < 4; ++nt) {
            int row = wc + nt * 16 + fl;
            bfv[nt] = *(const short8*)(Bs + row * 32 + ((ch ^ ((row >> 1) & 3)) * 8));
        }
        #pragma unroll
        for (int mt = 0; mt < 2; ++mt)
            #pragma unroll
            for (int nt = 0; nt < 4; ++nt)
                acc[mt][nt] = __builtin_amdgcn_mfma_f32_16x16x32_bf16(
                    af[mt], bfv[nt], acc[mt][nt], 0, 0, 0);
        __syncthreads();
    }

    float* Cf = (float*)Cb;
    unsigned short* Ch = (unsigned short*)Cb;
    const int rq = (lane >> 4) * 4;
    #pragma unroll
    for (int mt = 0; mt < 2; ++mt) {
        #pragma unroll
        for (int r = 0; r < 4; ++r) {
            long ro = (long)(m0 + wr + mt * 16 + rq + r) * N + n0 + wc + fl;
            #pragma unroll
            for (int nt = 0; nt < 4; ++nt) {
                float val = acc[mt][nt][r] * alpha;
                if (F32OUT) Cf[ro + nt * 16] = val;
                else        Ch[ro + nt * 16] = f2bf(val);
            }
        }
    }
}

// batched gemm64 with 1D grid + XCD swizzle: each XCD owns contiguous whole-batch
// chunks so the per-batch A/B panels (~2.5 MB) stay in its private L2.
// grid = BB * ntx * nty (must be % 8 == 0). n-tile fastest within a batch.
template<bool F32OUT>
__global__ __launch_bounds__(256) void gemm64x(
    const short* __restrict__ A, const short* __restrict__ Bt, void* __restrict__ C,
    int N, int K, long sA, long sB, long sC, float alpha, int ntx, int nty)
{
    const int wg  = xcd_swz(blockIdx.x, gridDim.x);
    const int per = ntx * nty;
    const int b   = wg / per;
    const int rem = wg - b * per;
    const int n0  = (rem % ntx) * 128;
    const int m0  = (rem / ntx) * 64;
    void* Cb = F32OUT ? (void*)((float*)C + (long)b * sC)
                      : (void*)((unsigned short*)C + (long)b * sC);
    gemm64_core<F32OUT>(A + (long)b * sA, Bt + (long)b * sB, Cb, m0, n0, N, K, alpha);
}

// =================== bf16 MFMA GEMM core: BM=128, BN=128, BK=32 (m97 structure) ===================
// 256 threads = 4 waves in 2x2; wave tile 64x64 (4x4 MFMA 16x16x32).
// Ab/Bb must already point at the tile origin (A + m0*K, Bt + n0*K). K % 32 == 0.
// LDS passed in by the caller: As = smem[0:4096), Bs = smem[4096:8192) (shorts).
__device__ __forceinline__ void gemm128_acc(const short* __restrict__ Ab,
                                            const short* __restrict__ Bb,
                                            int K, f32x4 acc[4][4],
                                            short* smem)
{
    short* As = smem;
    short* Bs = smem + 4096;
    const int tid  = threadIdx.x;
    const int lane = tid & 63;
    const int w    = tid >> 6;
    const int wr   = (w >> 1) * 64;
    const int wc   = (w & 1) * 64;

    const int srow = tid >> 2;                       // 0..63
    const int g    = ((tid & 3) ^ ((srow >> 1) & 3)) * 8;
    const short* gA0 = Ab + (long)srow * K + g;
    const short* gA1 = gA0 + (long)64 * K;
    const short* gB0 = Bb + (long)srow * K + g;
    const short* gB1 = gB0 + (long)64 * K;
    short* lA0 = As + tid * 8;
    short* lA1 = As + 2048 + tid * 8;
    short* lB0 = Bs + tid * 8;
    short* lB1 = Bs + 2048 + tid * 8;

    const int fl = lane & 15;
    const int ch = lane >> 4;

    for (int k0 = 0; k0 < K; k0 += 32) {
        GLDS16(gA0 + k0, lA0);
        GLDS16(gA1 + k0, lA1);
        GLDS16(gB0 + k0, lB0);
        GLDS16(gB1 + k0, lB1);
        __syncthreads();

        short8 af[4], bfv[4];
        #pragma unroll
        for (int mt = 0; mt < 4; ++mt) {
            int row = wr + mt * 16 + fl;
            af[mt] = *(const short8*)(As + row * 32 + ((ch ^ ((row >> 1) & 3)) * 8));
        }
        #pragma unroll
        for (int nt = 0; nt < 4; ++nt) {
            int row = wc + nt * 16 + fl;
            bfv[nt] = *(const short8*)(Bs + row * 32 + ((ch ^ ((row >> 1) & 3)) * 8));
        }
        #pragma unroll
        for (int mt = 0; mt < 4; ++mt)
            #pragma unroll
            for (int nt = 0; nt < 4; ++nt)
                acc[mt][nt] = __builtin_amdgcn_mfma_f32_16x16x32_bf16(
                    af[mt], bfv[nt], acc[mt][nt], 0, 0, 0);
        __syncthreads();
    }
}

// flat GEMM, M % 128 == 0, N % 128 == 0: C[M][N] = alpha * A[M][K] @ Bt[N][K]^T
// 1D grid, n-tile fastest after XCD swizzle.
template<bool F32OUT>
__global__ __launch_bounds__(256, 4) void gemm128(
    const short* __restrict__ A, const short* __restrict__ Bt, void* __restrict__ C,
    int N, int K, int ntiles_n, float alpha)
{
    __shared__ short smem[8192];
    const int wg = xcd_swz(blockIdx.x, gridDim.x);
    const int n0 = (wg % ntiles_n) * 128;
    const int m0 = (wg / ntiles_n) * 128;
    f32x4 acc[4][4] = {};
    gemm128_acc(A + (long)m0 * K, Bt + (long)n0 * K, K, acc, smem);

    const int tid = threadIdx.x, lane = tid & 63, w = tid >> 6;
    const int wr = (w >> 1) * 64, wc = (w & 1) * 64;
    const int fl = lane & 15, rq = (lane >> 4) * 4;
    float* Cf = (float*)C;
    unsigned short* Ch = (unsigned short*)C;
    #pragma unroll
    for (int mt = 0; mt < 4; ++mt) {
        #pragma unroll
        for (int r = 0; r < 4; ++r) {
            long ro = (long)(m0 + wr + mt * 16 + rq + r) * N + n0 + wc + fl;
            #pragma unroll
            for (int nt = 0; nt < 4; ++nt) {
                float val = acc[mt][nt][r] * alpha;
                if (F32OUT) Cf[ro + nt * 16] = val;
                else        Ch[ro + nt * 16] = f2bf(val);
            }
        }
    }
}

// =================== merged KV projection as ONE flat 128^2 GEMM ===================
// A = xsb||xisb viewed as [2*B*NS = 36864][CC]; Bt = WkT||WvT [1536][CC].
// Epilogue: C-tile staged through LDS (two 64-row halves, stride 136 shorts to
// spread banks, 16B-aligned) -> kk/vv written as coalesced dwordx4; v-half also
// written TRANSPOSED to vvT[b][c][n] as 64B-contiguous column runs (replaces the
// old 8B-scattered dual-write and the separate trans_vv kernel).
// Any 64-row half stays within one (b, xs/xi) group since 64 | NS and 64 | BB*NS.
// XCD swizzle: 3456 blocks = 8 x 432.
#define PKV_NT 12      // n-tiles = 1536/128
__global__ __launch_bounds__(256, 4) void proj_kv(
    const short* __restrict__ X, const short* __restrict__ WkvT,
    unsigned short* __restrict__ kkb, unsigned short* __restrict__ vvb,
    unsigned short* __restrict__ vvT)
{
    __shared__ short smem[64 * 136];   // 17408 B; first 8192 shorts double as As/Bs
    const int wg = xcd_swz(blockIdx.x, gridDim.x);
    const int n0 = (wg % PKV_NT) * 128;     // 0..1408
    const int m0 = (wg / PKV_NT) * 128;     // 0..36736
    f32x4 acc[4][4] = {};
    gemm128_acc(X + (long)m0 * CC, WkvT + (long)n0 * CC, CC, acc, smem);

    const int tid = threadIdx.x, lane = tid & 63, w = tid >> 6;
    const int wc = (w & 1) * 64;
    const int fl = lane & 15, rq = (lane >> 4) * 4;

    const bool isv = (n0 >= CC);
    unsigned short* cbase = isv ? vvb : kkb;
    const int j0base = isv ? n0 - CC : n0;

    #pragma unroll
    for (int h = 0; h < 2; ++h) {
        if ((w >> 1) == h) {
            // this half's 2 waves deposit their 64x128 bf16 sub-tile into LDS
            #pragma unroll
            for (int mt = 0; mt < 4; ++mt)
                #pragma unroll
                for (int nt = 0; nt < 4; ++nt)
                    #pragma unroll
                    for (int r = 0; r < 4; ++r)
                        smem[(mt * 16 + rq + r) * 136 + wc + nt * 16 + fl] =
                            (short)f2bf(acc[mt][nt][r]);
        }
        __syncthreads();
        const int row0 = m0 + h * 64;
        const int isxi = (row0 >= BB * NS) ? 1 : 0;
        const int r2   = row0 - isxi * (BB * NS);
        const int b    = r2 / NS;
        const int nb   = r2 - b * NS;

        // kk/vv: coalesced 16B stores; thread t -> row t>>2, chunks (t&3)+4i
        unsigned short* dst = cbase + (long)b * NS2 * CC + (long)isxi * NS * CC
                                    + (long)nb * CC + j0base;
        const int rowl = tid >> 2, cch = tid & 3;
        #pragma unroll
        for (int i = 0; i < 4; ++i)
            *(short8*)(dst + (long)rowl * CC + (cch + i * 4) * 8) =
                *(const short8*)(smem + rowl * 136 + (cch + i * 4) * 8);

        if (isv) {
            // vvT: thread t -> col c=t>>1, n-segment seg=(t&1)*32; 4x16B per thread
            const int c = tid >> 1, seg = (tid & 1) * 32;
            unsigned short* dT = vvT + ((long)b * CC + j0base + c) * NS2
                                     + (long)isxi * NS + nb + seg;
            #pragma unroll
            for (int i = 0; i < 4; ++i) {
                short8 v;
                #pragma unroll
                for (int e = 0; e < 8; ++e)
                    ((short*)&v)[e] = smem[(seg + i * 8 + e) * 136 + c];
                *(short8*)(dT + i * 8) = v;
            }
        }
        __syncthreads();
    }
}

// =================== input converts (fp32 -> bf16), merged ===================
__global__ void conv_in(const float* __restrict__ T, const float* __restrict__ x,
                        const float* __restrict__ xi,
                        unsigned short* __restrict__ Tb, unsigned short* __restrict__ xsb,
                        unsigned short* __restrict__ xisb)
{
    const int which = blockIdx.y;
    long i4 = ((long)blockIdx.x * 256 + threadIdx.x) * 4;
    const float* src; unsigned short* dst; long total; int rows, off, rpb;
    if (which == 0) { src = T;  dst = Tb;   total = (long)BB * NT * CC; rows = NT; off = 0;    rpb = NT; }
    else if (which == 1) { src = x;  dst = xsb;  total = (long)BB * NS * CC; rows = LX; off = TMPL; rpb = NS; }
    else            { src = xi; dst = xisb; total = (long)BB * NS * CC; rows = LX; off = TMPL; rpb = NS; }
    if (i4 >= total) return;
    int c   = (int)(i4 % CC);
    long rw = i4 / CC;
    int t   = (int)(rw % rpb);
    int b   = (int)(rw / rpb);
    const float4 f = *(const float4*)(src + ((long)b * rows + off + t) * CC + c);
    ushort4 o;
    o.x = f2bf(f.x); o.y = f2bf(f.y); o.z = f2bf(f.z); o.w = f2bf(f.w);
    *(ushort4*)(dst + i4) = o;
}

// fp32 W [CC][CC] -> bf16 W^T [CC][CC], 4 weights via blockIdx.z
__global__ void conv_wt4(const float* __restrict__ Wq, const float* __restrict__ Wk,
                         const float* __restrict__ Wv, const float* __restrict__ Wo,
                         unsigned short* __restrict__ WqT, unsigned short* __restrict__ WkT,
                         unsigned short* __restrict__ WvT, unsigned short* __restrict__ WoT)
{
    const float* W; unsigned short* WT;
    switch (blockIdx.z) {
        case 0: W = Wq; WT = WqT; break;
        case 1: W = Wk; WT = WkT; break;
        case 2: W = Wv; WT = WvT; break;
        default: W = Wo; WT = WoT; break;
    }
    __shared__ float tile[32][33];
    const int c0 = blockIdx.x * 32, r0 = blockIdx.y * 32;
    const int tx = threadIdx.x & 31, ty = threadIdx.x >> 5;
    #pragma unroll
    for (int i = 0; i < 4; ++i)
        tile[ty + 8 * i][tx] = W[(long)(r0 + ty + 8 * i) * CC + c0 + tx];
    __syncthreads();
    #pragma unroll
    for (int i = 0; i < 4; ++i)
        WT[(long)(c0 + ty + 8 * i) * CC + r0 + tx] = f2bf(tile[tx][ty + 8 * i]);
}

// =================== fused dual softmax + bf16 write + sign-pack ===================
// wave-per-row: 4 rows per 256-thread block, 9 values/lane/half, zero barriers.
// mask word i = ballot over lanes of (n = 64i + lane) -> matches posm/eqm layout.
__global__ __launch_bounds__(256) void softmax_pack(
    const float* __restrict__ P, unsigned short* __restrict__ Pb,
    u64* __restrict__ posm, u64* __restrict__ eqm)
{
    const int wv = threadIdx.x >> 6;
    const int lane = threadIdx.x & 63;
    const long r = (long)blockIdx.x * 4 + wv;    // b*NT + t
    const float* p = P + r * NS2;

    float a[9], bq[9];
    #pragma unroll
    for (int i = 0; i < 9; ++i) a[i]  = p[lane + 64 * i];
    #pragma unroll
    for (int i = 0; i < 9; ++i) bq[i] = p[NS + lane + 64 * i];

    float m1 = a[0], m2 = bq[0];
    #pragma unroll
    for (int i = 1; i < 9; ++i) { m1 = fmaxf(m1, a[i]); m2 = fmaxf(m2, bq[i]); }
    #pragma unroll
    for (int o = 32; o > 0; o >>= 1) {
        m1 = fmaxf(m1, __shfl_xor(m1, o, 64));
        m2 = fmaxf(m2, __shfl_xor(m2, o, 64));
    }
    float s1 = 0.f, s2 = 0.f;
    #pragma unroll
    for (int i = 0; i < 9; ++i) {
        a[i]  = __expf(a[i]  - m1); s1 += a[i];
        bq[i] = __expf(bq[i] - m2); s2 += bq[i];
    }
    #pragma unroll
    for (int o = 32; o > 0; o >>= 1) {
        s1 += __shfl_xor(s1, o, 64);
        s2 += __shfl_xor(s2, o, 64);
    }
    const float i1 = 1.f / s1, i2 = 1.f / s2;

    unsigned short* ob = Pb + r * NS2;
    u64* pm = posm + r * 9;
    u64* em = eqm  + r * 9;
    #pragma unroll
    for (int i = 0; i < 9; ++i) {
        float e = a[i] * i1, f = bq[i] * i2;
        ob[lane + 64 * i]      = f2bf(e);
        ob[NS + lane + 64 * i] = f2bf(f);
        float d = e - f;
        u64 PP = __ballot(d > 0.f);
        u64 EE = __ballot(d == 0.f);
        if (lane == 0) { pm[i] = PP; em[i] = EE; }
    }
}

// =================== fused count + x_s ===================
__global__ void xs_fused(const u64* __restrict__ posm, const u64* __restrict__ eqm,
                         const unsigned short* __restrict__ vvb, float* __restrict__ out)
{
    const int gid = blockIdx.x;          // b*NS + n
    const int b = gid / NS, n = gid - b * NS;
    const int tid = threadIdx.x;
    const int wsel = n >> 6, bit = n & 63;
    float ones = 0.f, eqc = 0.f;
    for (int t = tid; t < NT; t += 256) {
        long o = ((long)(b * NT + t)) * 9 + wsel;
        ones += (float)((posm[o] >> bit) & 1);
        eqc  += (float)((eqm[o]  >> bit) & 1);
    }
    ones = block_sum256(ones);
    eqc  = block_sum256(eqc);
    float rgb = ones * (1.f / NT), e = eqc * (1.f / NT);
    float c1 = rgb + e;
    float c2 = (1.f - rgb - e) + e;
    const unsigned* pv  = (const unsigned*)(vvb + ((long)b * NS2 + n) * CC);
    const unsigned* pvi = (const unsigned*)(vvb + ((long)b * NS2 + n + NS) * CC);
    float* po = out + ((long)b * NS + n) * CC;
    for (int idx = tid; idx < CC / 2; idx += 256) {
        unsigned a = pv[idx], bb = pvi[idx];
        float2 o2;
        o2.x = bf2f((unsigned short)(a & 0xFFFF)) * c1 + bf2f((unsigned short)(bb & 0xFFFF)) * c2;
        o2.y = bf2f((unsigned short)(a >> 16))    * c1 + bf2f((unsigned short)(bb >> 16))    * c2;
        *(float2*)(po + 2 * idx) = o2;
    }
}

// =================== T_new = LayerNorm(T + S2) ===================
__global__ void add_ln(const float* __restrict__ T, const float* __restrict__ S2,
                       const float* __restrict__ gamma, const float* __restrict__ beta,
                       float* __restrict__ out)
{
    const long r = blockIdx.x;            // b*NT + t
    const int tid = threadIdx.x;
    const float* tp = T  + r * CC;
    const float* sp = S2 + r * CC;
    float h[3];
    float sum = 0.f;
    #pragma unroll
    for (int i = 0; i < 3; ++i) {
        h[i] = tp[tid + 256 * i] + sp[tid + 256 * i];
        sum += h[i];
    }
    sum = block_sum256(sum);
    float mu = sum * (1.f / CC);
    float varp = 0.f;
    #pragma unroll
    for (int i = 0; i < 3; ++i) { float d = h[i] - mu; varp += d * d; }
    varp = block_sum256(varp);
    float inv = rsqrtf(varp * (1.f / CC) + LN_EPS);
    #pragma unroll
    for (int i = 0; i < 3; ++i) {
        int c = tid + 256 * i;
        out[r * CC + c] = (h[i] - mu) * inv * gamma[c] + beta[c];
    }
}

// =================== launch ===================
extern "C" void kernel_launch(void* const* d_in, const int* in_sizes, int n_in,
                              void* d_out, int out_size, void* d_ws, size_t ws_size,
                              hipStream_t stream) {
    const float* T     = (const float*)d_in[0];
    const float* x     = (const float*)d_in[1];
    const float* xi    = (const float*)d_in[2];
    const float* Wq    = (const float*)d_in[3];
    const float* Wk    = (const float*)d_in[4];
    const float* Wv    = (const float*)d_in[5];
    const float* Wout  = (const float*)d_in[6];
    const float* gamma = (const float*)d_in[7];
    const float* beta  = (const float*)d_in[8];
    float* out = (float*)d_out;

    // ---- workspace layout (bytes), ~288 MB ----
    const long B_T  = (long)BB * NT * CC * 2;         // 15.7 MB (Tb; later Sb)
    const long B_KK = (long)BB * NS2 * CC * 2;        // 56.6 MB
    const long B_WT = (long)CC * CC * 2;              // 1.18 MB each
    const long B_XS = (long)BB * NS * CC * 2;         // 28.3 MB each; pair overlaid by P fp32 (47.2 MB)
    const long B_PB = (long)BB * NT * NS2 * 2;        // 23.6 MB
    const long B_MK = (long)BB * NT * 9 * 8;          // 0.74 MB each

    char* cur = (char*)d_ws;
    unsigned short* Tb   = (unsigned short*)cur; cur += B_T;
    unsigned short* qb   = (unsigned short*)cur; cur += B_T;
    unsigned short* kkb  = (unsigned short*)cur; cur += B_KK;
    unsigned short* WqT  = (unsigned short*)cur; cur += B_WT;
    unsigned short* WkT  = (unsigned short*)cur; cur += B_WT;   // NOTE: WkT||WvT must stay
    unsigned short* WvT  = (unsigned short*)cur; cur += B_WT;   //       adjacent (proj_kv B operand)
    unsigned short* WoT  = (unsigned short*)cur; cur += B_WT;
    unsigned short* vvb  = (unsigned short*)cur; cur += B_KK;
    unsigned short* vvT  = (unsigned short*)cur; cur += B_KK;
    unsigned short* xsb  = (unsigned short*)cur;                // NOTE: xsb||xisb contiguous
    unsigned short* xisb = xsb + (long)BB * NS * CC;  cur += 2 * B_XS;
    unsigned short* Pb   = (unsigned short*)cur; cur += B_PB;
    u64* posm            = (u64*)cur; cur += B_MK;
    u64* eqm             = (u64*)cur; cur += B_MK;
    if ((size_t)(cur - (char*)d_ws) > ws_size) return;

    float* P  = (float*)xsb;    // xsb/xisb dead after projections; 47.2 <= 56.6 MB
    unsigned short* Sb = Tb;    // Tb dead after q GEMM
    float* S2 = (float*)vvb;    // vvb dead after xs_fused; 31.5 <= 56.6 MB

    const float scale = 1.0f / sqrtf((float)CC);
    dim3 blk(256);

    // 1. converts (2 dispatches)
    conv_in<<<dim3((BB * NS * CC) / 1024, 3), blk, 0, stream>>>(T, x, xi, Tb, xsb, xisb);
    conv_wt4<<<dim3(CC / 32, CC / 32, 4), blk, 0, stream>>>(Wq, Wk, Wv, Wout, WqT, WkT, WvT, WoT);

    // 2. merged KV projections as ONE flat GEMM: M=36864, N=1536, K=768
    //    3456 blocks = 8 XCD chunks x 432; LDS-staged coalesced epilogue + vvT.
    proj_kv<<<dim3(((2 * CC) / 128) * ((2 * BB * NS) / 128)), blk, 0, stream>>>(
        (const short*)xsb, (const short*)WkT, kkb, vvb, vvT);

    // 3. q = T @ Wq  (flat across batch: M = B*NT = 10240; 480 blocks = 8 x 60)
    gemm128<false><<<dim3((CC / 128) * ((BB * NT) / 128)), blk, 0, stream>>>(
        (const short*)Tb, (const short*)WqT, qb, CC, CC, CC / 128, 1.f);

    // 4. logits (fp32): P = scale * q @ [k|ki]^T
    //    1440 blocks = 8 XCDs x 180 (4 whole batches per XCD; 2.3 MB/batch in L2)
    gemm64x<true><<<dim3(BB * (NS2 / 128) * (NT / 64)), blk, 0, stream>>>(
        (const short*)qb, (const short*)kkb, P, NS2, CC,
        (long)NT * CC, (long)NS2 * CC, (long)NT * NS2, scale, NS2 / 128, NT / 64);

    // 5. dual softmax + bf16 P + sign masks (wave-per-row; 2560 blocks)
    softmax_pack<<<dim3((BB * NT) / 4), blk, 0, stream>>>(P, Pb, posm, eqm);

    // 6. fused count + x_s -> d_out[0 : B*NS*CC]
    xs_fused<<<BB * NS, blk, 0, stream>>>(posm, eqm, vvb, out);

    // 7. S = [aw|awi] @ [v;vi]   (bf16, K=1152)
    //    960 blocks = 8 XCDs x 120 (4 whole batches per XCD; 2.5 MB/batch in L2)
    gemm64x<false><<<dim3(BB * (CC / 128) * (NT / 64)), blk, 0, stream>>>(
        (const short*)Pb, (const short*)vvT, Sb, CC, NS2,
        (long)NT * NS2, (long)CC * NS2, (long)NT * CC, 1.f, CC / 128, NT / 64);

    // 8. S2 = S @ Wout  (fp32, flat: M = B*NT = 10240)
    gemm128<true><<<dim3((CC / 128) * ((BB * NT) / 128)), blk, 0, stream>>>(
        (const short*)Sb, (const short*)WoT, S2, CC, CC, CC / 128, 1.f);

    // 9. T_new = LN(T + S2) -> d_out tail
    add_ln<<<BB * NT, blk, 0, stream>>>(T, S2, gamma, beta, out + (long)BB * NS * CC);
}